// Round 1
// baseline (7290.008 us; speedup 1.0000x reference)
//
#include <hip/hip_runtime.h>
#include <cstdint>
#include <cstddef>

#define GN    32768
#define GG    64
#define NNODE 512
#define EE    256
#define LL    4
#define DFFN  2048
#define NHH   8
#define HD    32
#define NEDGE 524288
#define KSEL  128
#define DIN   128

// ---------------------------------------------------------------------------
// Generic NT GEMM: C[M,N] = A[M,K] @ B[N,K]^T + bias[N]   (fp32, 64x64 tile)
// ---------------------------------------------------------------------------
__global__ __launch_bounds__(256) void gemm_nt(const float* __restrict__ A,
                                               const float* __restrict__ B,
                                               const float* __restrict__ bias,
                                               float* __restrict__ C,
                                               int M, int N, int K) {
  __shared__ float As[16][64];
  __shared__ float Bs[16][64];
  const int tid = threadIdx.x;
  const int tx = tid & 15, ty = tid >> 4;
  const int bn = blockIdx.x * 64, bm = blockIdx.y * 64;
  const int lr = tid >> 2;          // 0..63
  const int lc = (tid & 3) << 2;    // 0,4,8,12
  const float* Ap = A + (size_t)(bm + lr) * K + lc;
  const float* Bp = B + (size_t)(bn + lr) * K + lc;
  float acc[4][4] = {};
  for (int k0 = 0; k0 < K; k0 += 16) {
    float4 av = *(const float4*)(Ap + k0);
    float4 bv = *(const float4*)(Bp + k0);
    As[lc + 0][lr] = av.x; As[lc + 1][lr] = av.y; As[lc + 2][lr] = av.z; As[lc + 3][lr] = av.w;
    Bs[lc + 0][lr] = bv.x; Bs[lc + 1][lr] = bv.y; Bs[lc + 2][lr] = bv.z; Bs[lc + 3][lr] = bv.w;
    __syncthreads();
#pragma unroll
    for (int kk = 0; kk < 16; ++kk) {
      float4 a4 = *(const float4*)&As[kk][ty << 2];
      float4 b4 = *(const float4*)&Bs[kk][tx << 2];
      float aa[4] = {a4.x, a4.y, a4.z, a4.w};
      float bb[4] = {b4.x, b4.y, b4.z, b4.w};
#pragma unroll
      for (int i = 0; i < 4; ++i)
#pragma unroll
        for (int j = 0; j < 4; ++j) acc[i][j] += aa[i] * bb[j];
    }
    __syncthreads();
  }
  float4 bsv = *(const float4*)&bias[bn + (tx << 2)];
  float bb[4] = {bsv.x, bsv.y, bsv.z, bsv.w};
#pragma unroll
  for (int i = 0; i < 4; ++i) {
    float4 o;
    o.x = acc[i][0] + bb[0];
    o.y = acc[i][1] + bb[1];
    o.z = acc[i][2] + bb[2];
    o.w = acc[i][3] + bb[3];
    *(float4*)&C[(size_t)(bm + (ty << 2) + i) * N + bn + (tx << 2)] = o;
  }
}

// ---------------------------------------------------------------------------
// Flash-style attention: one block per (graph, head). K/V staged in LDS in
// tiles of 256 keys (2x32KB = 64KB LDS -> 2 blocks/CU). Each thread owns two
// q rows with online softmax; hot-loop LDS reads are wave-uniform broadcasts.
// ---------------------------------------------------------------------------
__global__ __launch_bounds__(256) void attn_kernel(const float* __restrict__ qkv,
                                                   float* __restrict__ ob) {
  __shared__ float Ks[256][32];
  __shared__ float Vs[256][32];
  const int g = blockIdx.x >> 3, hh = blockIdx.x & 7;
  const int tid = threadIdx.x;
  const float* base = qkv + (size_t)g * NNODE * 768;
  const float scale = 0.17677669529663687f;  // 1/sqrt(32)

  float q0[32], q1[32], o0[32], o1[32];
  {
    const float* q0p = base + (size_t)tid * 768 + hh * HD;
    const float* q1p = base + (size_t)(tid + 256) * 768 + hh * HD;
#pragma unroll
    for (int c = 0; c < 32; c += 4) {
      float4 a = *(const float4*)(q0p + c);
      q0[c] = a.x * scale; q0[c + 1] = a.y * scale; q0[c + 2] = a.z * scale; q0[c + 3] = a.w * scale;
      float4 b = *(const float4*)(q1p + c);
      q1[c] = b.x * scale; q1[c + 1] = b.y * scale; q1[c + 2] = b.z * scale; q1[c + 3] = b.w * scale;
    }
  }
#pragma unroll
  for (int c = 0; c < 32; ++c) { o0[c] = 0.f; o1[c] = 0.f; }
  float m0 = -1e30f, m1 = -1e30f, l0 = 0.f, l1 = 0.f;

  const int rst = tid >> 3, cst = (tid & 7) << 2;
  for (int tile = 0; tile < 2; ++tile) {
    __syncthreads();
#pragma unroll
    for (int jj = 0; jj < 8; ++jj) {
      int r = (jj << 5) + rst;
      const float* rp = base + (size_t)(tile * 256 + r) * 768 + hh * HD + cst;
      *(float4*)&Ks[r][cst] = *(const float4*)(rp + 256);
      *(float4*)&Vs[r][cst] = *(const float4*)(rp + 512);
    }
    __syncthreads();
    for (int j = 0; j < 256; ++j) {
      const float* kr = Ks[j];
      float p0a = 0.f, p0b = 0.f, p0c = 0.f, p0d = 0.f;
      float p1a = 0.f, p1b = 0.f, p1c = 0.f, p1d = 0.f;
#pragma unroll
      for (int c = 0; c < 32; c += 4) {
        float4 k4 = *(const float4*)(kr + c);
        p0a += q0[c] * k4.x; p0b += q0[c + 1] * k4.y; p0c += q0[c + 2] * k4.z; p0d += q0[c + 3] * k4.w;
        p1a += q1[c] * k4.x; p1b += q1[c + 1] * k4.y; p1c += q1[c + 2] * k4.z; p1d += q1[c + 3] * k4.w;
      }
      float d0 = (p0a + p0b) + (p0c + p0d);
      float d1 = (p1a + p1b) + (p1c + p1d);
      if (d0 > m0) {
        float corr = __expf(m0 - d0); m0 = d0; l0 *= corr;
#pragma unroll
        for (int c = 0; c < 32; ++c) o0[c] *= corr;
      }
      float e0 = __expf(d0 - m0); l0 += e0;
      if (d1 > m1) {
        float corr = __expf(m1 - d1); m1 = d1; l1 *= corr;
#pragma unroll
        for (int c = 0; c < 32; ++c) o1[c] *= corr;
      }
      float e1 = __expf(d1 - m1); l1 += e1;
      const float* vr = Vs[j];
#pragma unroll
      for (int c = 0; c < 32; c += 4) {
        float4 v4 = *(const float4*)(vr + c);
        o0[c] += e0 * v4.x; o0[c + 1] += e0 * v4.y; o0[c + 2] += e0 * v4.z; o0[c + 3] += e0 * v4.w;
        o1[c] += e1 * v4.x; o1[c + 1] += e1 * v4.y; o1[c + 2] += e1 * v4.z; o1[c + 3] += e1 * v4.w;
      }
    }
  }
  float i0 = 1.0f / l0, i1 = 1.0f / l1;
  float* w0 = ob + (size_t)(g * NNODE + tid) * EE + hh * HD;
  float* w1p = ob + (size_t)(g * NNODE + tid + 256) * EE + hh * HD;
#pragma unroll
  for (int c = 0; c < 32; c += 4) {
    float4 a; a.x = o0[c] * i0; a.y = o0[c + 1] * i0; a.z = o0[c + 2] * i0; a.w = o0[c + 3] * i0;
    *(float4*)(w0 + c) = a;
    float4 b; b.x = o1[c] * i1; b.y = o1[c + 1] * i1; b.z = o1[c + 2] * i1; b.w = o1[c + 3] * i1;
    *(float4*)(w1p + c) = b;
  }
}

// ---------------------------------------------------------------------------
// Residual + LayerNorm (two-pass, matches reference): h = LN(h + t)*w + b
// One wave per row (E=256, 4 elements/lane).
// ---------------------------------------------------------------------------
__global__ __launch_bounds__(256) void ln_res_kernel(float* __restrict__ h,
                                                     const float* __restrict__ t,
                                                     const float* __restrict__ w,
                                                     const float* __restrict__ b) {
  int row = blockIdx.x * 4 + (threadIdx.x >> 6);
  int lane = threadIdx.x & 63;
  size_t off = (size_t)row * EE + (lane << 2);
  float4 hv = *(const float4*)&h[off];
  float4 tv = *(const float4*)&t[off];
  float v0 = hv.x + tv.x, v1 = hv.y + tv.y, v2 = hv.z + tv.z, v3 = hv.w + tv.w;
  float s = (v0 + v1) + (v2 + v3);
#pragma unroll
  for (int m = 32; m > 0; m >>= 1) s += __shfl_xor(s, m);
  float mu = s * (1.0f / 256.0f);
  float d0 = v0 - mu, d1 = v1 - mu, d2 = v2 - mu, d3 = v3 - mu;
  float s2 = (d0 * d0 + d1 * d1) + (d2 * d2 + d3 * d3);
#pragma unroll
  for (int m = 32; m > 0; m >>= 1) s2 += __shfl_xor(s2, m);
  float rs = 1.0f / sqrtf(s2 * (1.0f / 256.0f) + 1e-5f);
  float4 wv = *(const float4*)&w[lane << 2];
  float4 bv = *(const float4*)&b[lane << 2];
  float4 o;
  o.x = d0 * rs * wv.x + bv.x;
  o.y = d1 * rs * wv.y + bv.y;
  o.z = d2 * rs * wv.z + bv.z;
  o.w = d3 * rs * wv.w + bv.w;
  *(float4*)&h[off] = o;
}

// ---------------------------------------------------------------------------
// Fused FFN + residual + LayerNorm.
// delta = relu(h@W1^T + b1) @ W2^T + b2 ; h = LN(h + delta)*w + b
// One block per 64 rows. DFF streamed in chunks of 64 (32 chunks); each chunk:
// phase1 (64x64x256 GEMM -> relu -> Ts), phase2 (accumulate into 64x256 regs).
// 4x16KB LDS = 64KB -> 2 blocks/CU. Hot loops: ds_read_b128, <=2-way conflicts.
// ---------------------------------------------------------------------------
__global__ __launch_bounds__(256) void ff_ln_kernel(float* __restrict__ h,
    const float* __restrict__ w1, const float* __restrict__ b1,
    const float* __restrict__ w2, const float* __restrict__ b2,
    const float* __restrict__ lnw, const float* __restrict__ lnb) {
  __shared__ float Hs[64][64];   // [k_sub][m]
  __shared__ float W1s[64][64];  // [k_sub][d]
  __shared__ float Ts[64][64];   // [d][m]
  __shared__ float W2s[64][64];  // [d][e_sub]
  const int tid = threadIdx.x;
  const int tx = tid & 15, ty = tid >> 4;
  const size_t rowbase = (size_t)blockIdx.x * 64;
  const int sr = tid >> 2;          // 0..63
  const int sq = (tid & 3) << 2;    // 0,4,8,12
  float acc[4][4][4] = {};          // [row i][e-block jj][e j]

  for (int ch = 0; ch < 32; ++ch) {
    const float* w1c = w1 + (size_t)ch * 64 * 256;
    float t[4][4] = {};
    for (int ks = 0; ks < 4; ++ks) {
      __syncthreads();
#pragma unroll
      for (int u = 0; u < 4; ++u) {
        int k4 = sq + u * 16;
        float4 av = *(const float4*)&h[(rowbase + sr) * 256 + ks * 64 + k4];
        Hs[k4 + 0][sr] = av.x; Hs[k4 + 1][sr] = av.y; Hs[k4 + 2][sr] = av.z; Hs[k4 + 3][sr] = av.w;
        float4 wv = *(const float4*)&w1c[(size_t)sr * 256 + ks * 64 + k4];
        W1s[k4 + 0][sr] = wv.x; W1s[k4 + 1][sr] = wv.y; W1s[k4 + 2][sr] = wv.z; W1s[k4 + 3][sr] = wv.w;
      }
      __syncthreads();
#pragma unroll 4
      for (int k = 0; k < 64; ++k) {
        float4 a4 = *(const float4*)&Hs[k][ty << 2];
        float4 b4 = *(const float4*)&W1s[k][tx << 2];
        float aa[4] = {a4.x, a4.y, a4.z, a4.w};
        float bb[4] = {b4.x, b4.y, b4.z, b4.w};
#pragma unroll
        for (int i = 0; i < 4; ++i)
#pragma unroll
          for (int j = 0; j < 4; ++j) t[i][j] += aa[i] * bb[j];
      }
    }
    float4 b1v = *(const float4*)&b1[ch * 64 + (tx << 2)];
    float bb1[4] = {b1v.x, b1v.y, b1v.z, b1v.w};
#pragma unroll
    for (int i = 0; i < 4; ++i)
#pragma unroll
      for (int j = 0; j < 4; ++j)
        Ts[(tx << 2) + j][(ty << 2) + i] = fmaxf(t[i][j] + bb1[j], 0.0f);
#pragma unroll 1
    for (int jj = 0; jj < 4; ++jj) {
      __syncthreads();  // Ts complete / previous W2s reads done
#pragma unroll
      for (int u = 0; u < 4; ++u) {
        int d4 = sq + u * 16;
        float4 wv = *(const float4*)&w2[(size_t)(jj * 64 + sr) * 2048 + ch * 64 + d4];
        W2s[d4 + 0][sr] = wv.x; W2s[d4 + 1][sr] = wv.y; W2s[d4 + 2][sr] = wv.z; W2s[d4 + 3][sr] = wv.w;
      }
      __syncthreads();
#pragma unroll 4
      for (int d = 0; d < 64; ++d) {
        float4 a4 = *(const float4*)&Ts[d][ty << 2];
        float4 w4 = *(const float4*)&W2s[d][tx << 2];
        float aa[4] = {a4.x, a4.y, a4.z, a4.w};
        float ww[4] = {w4.x, w4.y, w4.z, w4.w};
#pragma unroll
        for (int i = 0; i < 4; ++i)
#pragma unroll
          for (int j = 0; j < 4; ++j) acc[i][jj][j] += aa[i] * ww[j];
      }
    }
  }

  // ---- epilogue: +b2, +residual, LayerNorm, write h in place ----
  __syncthreads();
  float* red1 = &W1s[0][0];
  float* red2 = &W2s[0][0];
  float* MuA = &Ts[0][0];
  float* RsA = MuA + 64;
  float4 b2v[4], lw4[4], lb4[4];
#pragma unroll
  for (int jj = 0; jj < 4; ++jj) {
    b2v[jj] = *(const float4*)&b2[jj * 64 + (tx << 2)];
    lw4[jj] = *(const float4*)&lnw[jj * 64 + (tx << 2)];
    lb4[jj] = *(const float4*)&lnb[jj * 64 + (tx << 2)];
  }
#pragma unroll
  for (int i = 0; i < 4; ++i) {
    float s = 0.f, s2 = 0.f;
#pragma unroll
    for (int jj = 0; jj < 4; ++jj) {
      float4 hr = *(const float4*)&h[(rowbase + (ty << 2) + i) * 256 + jj * 64 + (tx << 2)];
      float hb[4] = {hr.x, hr.y, hr.z, hr.w};
      float bz[4] = {b2v[jj].x, b2v[jj].y, b2v[jj].z, b2v[jj].w};
#pragma unroll
      for (int j = 0; j < 4; ++j) {
        float v = acc[i][jj][j] + bz[j] + hb[j];
        acc[i][jj][j] = v;
        s += v; s2 += v * v;
      }
    }
    red1[((ty << 2) + i) * 16 + tx] = s;
    red2[((ty << 2) + i) * 16 + tx] = s2;
  }
  __syncthreads();
  if (tid < 64) {
    float s = 0.f, s2 = 0.f;
#pragma unroll
    for (int xx = 0; xx < 16; ++xx) { s += red1[tid * 16 + xx]; s2 += red2[tid * 16 + xx]; }
    float mu = s * (1.0f / 256.0f);
    float var = s2 * (1.0f / 256.0f) - mu * mu;
    MuA[tid] = mu;
    RsA[tid] = 1.0f / sqrtf(var + 1e-5f);
  }
  __syncthreads();
#pragma unroll
  for (int i = 0; i < 4; ++i) {
    float mu = MuA[(ty << 2) + i];
    float rs = RsA[(ty << 2) + i];
#pragma unroll
    for (int jj = 0; jj < 4; ++jj) {
      float4 o;
      o.x = (acc[i][jj][0] - mu) * rs * lw4[jj].x + lb4[jj].x;
      o.y = (acc[i][jj][1] - mu) * rs * lw4[jj].y + lb4[jj].y;
      o.z = (acc[i][jj][2] - mu) * rs * lw4[jj].z + lb4[jj].z;
      o.w = (acc[i][jj][3] - mu) * rs * lw4[jj].w + lb4[jj].w;
      *(float4*)&h[(rowbase + (ty << 2) + i) * 256 + jj * 64 + (tx << 2)] = o;
    }
  }
}

// ---------------------------------------------------------------------------
// scores -> sigmoid -> probs. One wave per row.
// ---------------------------------------------------------------------------
__global__ __launch_bounds__(256) void score_kernel(const float* __restrict__ h,
                                                    const float* __restrict__ sw,
                                                    const float* __restrict__ sb,
                                                    float* __restrict__ probs) {
  int row = blockIdx.x * 4 + (threadIdx.x >> 6);
  int lane = threadIdx.x & 63;
  float4 a = *(const float4*)&h[(size_t)row * EE + (lane << 2)];
  float4 w = *(const float4*)&sw[lane << 2];
  float s = (a.x * w.x + a.y * w.y) + (a.z * w.z + a.w * w.w);
#pragma unroll
  for (int m = 32; m > 0; m >>= 1) s += __shfl_xor(s, m);
  if (lane == 0) {
    float sc = s + sb[0];
    probs[row] = 1.0f / (1.0f + expf(-sc));
  }
}

// ---------------------------------------------------------------------------
// Per-graph exact top-k with jax.lax.top_k tie semantics (lower index wins):
// bitonic sort of (prob_bits, ~idx) keys, then flags + prefix-scan for the
// ascending sampled_nodes, and straight-through probs_f.
// Outputs: ew at [0, NE), sampled_nodes (as float) at [NE, NE+8192),
//          probs_f at [NE+8192, NE+8192+GN).
// ---------------------------------------------------------------------------
__global__ __launch_bounds__(256) void topk_kernel(const float* __restrict__ probs,
                                                   float* __restrict__ out) {
  __shared__ unsigned long long keys[NNODE];
  __shared__ float pv[NNODE];
  __shared__ int flags[NNODE];
  __shared__ int sc[NNODE];
  const int g = blockIdx.x, tid = threadIdx.x;
  for (int i = tid; i < NNODE; i += 256) {
    float p = probs[g * NNODE + i];
    pv[i] = p;
    keys[i] = ((unsigned long long)__float_as_uint(p) << 32) |
              (unsigned long long)(~(unsigned)i);
    flags[i] = 0;
  }
  for (int k = 2; k <= NNODE; k <<= 1) {
    for (int j = k >> 1; j > 0; j >>= 1) {
      __syncthreads();
      for (int i = tid; i < NNODE; i += 256) {
        int ixj = i ^ j;
        if (ixj > i) {
          unsigned long long a = keys[i], bq = keys[ixj];
          bool desc = ((i & k) == 0);
          bool sw = desc ? (a < bq) : (a > bq);
          if (sw) { keys[i] = bq; keys[ixj] = a; }
        }
      }
    }
  }
  __syncthreads();
  if (tid < KSEL) {
    unsigned idx = ~(unsigned)(keys[tid] & 0xFFFFFFFFull);
    flags[idx] = 1;
  }
  __syncthreads();
  sc[tid] = flags[tid];
  sc[tid + 256] = flags[tid + 256];
  for (int off = 1; off < NNODE; off <<= 1) {
    __syncthreads();
    int x0 = (tid >= off) ? sc[tid - off] : 0;
    int x1 = sc[tid + 256 - off];
    int b0 = sc[tid], b1 = sc[tid + 256];
    __syncthreads();
    sc[tid] = b0 + x0;
    sc[tid + 256] = b1 + x1;
  }
  __syncthreads();
  for (int i = tid; i < NNODE; i += 256) {
    float p = pv[i];
    int f = flags[i];
    float ind = ((float)f - p) + p;   // straight-through forward value
    float pf = p * ind;               // == 0 exactly when not selected
    out[NEDGE + GG * KSEL + g * NNODE + i] = pf;
    if (f) out[NEDGE + g * KSEL + (sc[i] - 1)] = (float)(g * NNODE + i);
  }
}

// ---------------------------------------------------------------------------
// ew[e] = edge_weights[e] * pf[src] * pf[dst]
// ---------------------------------------------------------------------------
__global__ __launch_bounds__(256) void edge_kernel(const int* __restrict__ ei,
                                                   const float* __restrict__ w,
                                                   float* __restrict__ out) {
  int e = blockIdx.x * 256 + threadIdx.x;
  const float* pf = out + NEDGE + GG * KSEL;
  out[e] = w[e] * pf[ei[e]] * pf[ei[NEDGE + e]];
}

// ---------------------------------------------------------------------------
extern "C" void kernel_launch(void* const* d_in, const int* in_sizes, int n_in,
                              void* d_out, int out_size, void* d_ws, size_t ws_size,
                              hipStream_t stream) {
  (void)in_sizes; (void)n_in; (void)out_size; (void)ws_size;
  const float* x     = (const float*)d_in[0];
  const int*   ei    = (const int*)d_in[1];
  const float* ewts  = (const float*)d_in[2];
  const float* emb_w = (const float*)d_in[3];
  const float* emb_b = (const float*)d_in[4];
  const float* qkv_w = (const float*)d_in[5];
  const float* qkv_b = (const float*)d_in[6];
  const float* out_w = (const float*)d_in[7];
  const float* out_b = (const float*)d_in[8];
  const float* ln1_w = (const float*)d_in[9];
  const float* ln1_b = (const float*)d_in[10];
  const float* ln2_w = (const float*)d_in[11];
  const float* ln2_b = (const float*)d_in[12];
  const float* ff1_w = (const float*)d_in[13];
  const float* ff1_b = (const float*)d_in[14];
  const float* ff2_w = (const float*)d_in[15];
  const float* ff2_b = (const float*)d_in[16];
  const float* sc_w  = (const float*)d_in[17];
  const float* sc_b  = (const float*)d_in[18];

  float* out = (float*)d_out;
  float* ws  = (float*)d_ws;
  float* h     = ws;                          // 32768*256
  float* qkvb  = h + (size_t)GN * EE;         // 32768*768
  float* ob    = qkvb + (size_t)GN * 768;     // 32768*256
  float* tmpb  = qkvb;                        // alias: qkv dead after attention
  float* probs = ob + (size_t)GN * EE;        // 32768

  // embed: h = x @ emb_w^T + emb_b
  gemm_nt<<<dim3(EE / 64, GN / 64), 256, 0, stream>>>(x, emb_w, emb_b, h, GN, EE, DIN);

  for (int l = 0; l < LL; ++l) {
    gemm_nt<<<dim3(768 / 64, GN / 64), 256, 0, stream>>>(
        h, qkv_w + (size_t)l * 768 * EE, qkv_b + l * 768, qkvb, GN, 768, EE);
    attn_kernel<<<GG * NHH, 256, 0, stream>>>(qkvb, ob);
    gemm_nt<<<dim3(EE / 64, GN / 64), 256, 0, stream>>>(
        ob, out_w + (size_t)l * EE * EE, out_b + l * EE, tmpb, GN, EE, EE);
    ln_res_kernel<<<GN / 4, 256, 0, stream>>>(h, tmpb, ln1_w + l * EE, ln1_b + l * EE);
    ff_ln_kernel<<<GN / 64, 256, 0, stream>>>(
        h, ff1_w + (size_t)l * DFFN * EE, ff1_b + l * DFFN,
        ff2_w + (size_t)l * EE * DFFN, ff2_b + l * EE,
        ln2_w + l * EE, ln2_b + l * EE);
  }

  score_kernel<<<GN / 4, 256, 0, stream>>>(h, sc_w, sc_b, probs);
  topk_kernel<<<GG, 256, 0, stream>>>(probs, out);
  edge_kernel<<<NEDGE / 256, 256, 0, stream>>>(ei, ewts, out);
}

// Round 2
// 3919.321 us; speedup vs baseline: 1.8600x; 1.8600x over previous
//
#include <hip/hip_runtime.h>
#include <cstdint>
#include <cstddef>

#define GN    32768
#define GG    64
#define NNODE 512
#define EE    256
#define LL    4
#define DFFN  2048
#define NHH   8
#define HD    32
#define NEDGE 524288
#define KSEL  128
#define DIN   128
#define CHUNK 8192

typedef __attribute__((ext_vector_type(8))) short short8;
typedef __attribute__((ext_vector_type(4))) float floatx4;

// ---- bf16 helpers (RNE) ---------------------------------------------------
__device__ __forceinline__ unsigned short f2bf(float x) {
  unsigned u = __float_as_uint(x);
  u = (u + 0x7FFFu + ((u >> 16) & 1u)) >> 16;
  return (unsigned short)u;
}
__device__ __forceinline__ float bf2f(unsigned short u) {
  return __uint_as_float((unsigned)u << 16);
}

// async global->LDS, 16B per lane
__device__ __forceinline__ void ld_lds16(const ushort* g, ushort* l) {
  __builtin_amdgcn_global_load_lds(
      (const __attribute__((address_space(1))) unsigned int*)g,
      (__attribute__((address_space(3))) unsigned int*)l, 16, 0, 0);
}

// ---------------------------------------------------------------------------
// split fp32 -> (hi, lo) bf16 pair, 4 elements/thread
// ---------------------------------------------------------------------------
__global__ __launch_bounds__(256) void split_kernel(const float* __restrict__ in,
                                                    ushort* __restrict__ hi,
                                                    ushort* __restrict__ lo, int n4) {
  int i = blockIdx.x * 256 + threadIdx.x;
  if (i >= n4) return;
  float4 v = ((const float4*)in)[i];
  ushort4 hv, lv;
  float t[4] = {v.x, v.y, v.z, v.w};
  unsigned short hb;
  hb = f2bf(t[0]); hv.x = hb; lv.x = f2bf(t[0] - bf2f(hb));
  hb = f2bf(t[1]); hv.y = hb; lv.y = f2bf(t[1] - bf2f(hb));
  hb = f2bf(t[2]); hv.z = hb; lv.z = f2bf(t[2] - bf2f(hb));
  hb = f2bf(t[3]); hv.w = hb; lv.w = f2bf(t[3] - bf2f(hb));
  ((ushort4*)hi)[i] = hv;
  ((ushort4*)lo)[i] = lv;
}

// ---------------------------------------------------------------------------
// Split-bf16 MFMA GEMM: C[M,N] = split(A)[M,K] @ split(B)[N,K]^T + bias[N]
// 3-term Markidis: Ahi*Bhi + Ahi*Blo + Alo*Bhi, fp32 acc in MFMA.
// Tile BM x BN (BK=32 bf16), 256 threads = 4 waves in 2x2, wave tile
// (BM/2)x(BN/2) of 16x16x32 MFMAs. m97-style global_load_lds width-16 staging.
// MODE bit0: store fp32 C; bit1: store split bf16 (c_hi/c_lo). RELU optional.
// ---------------------------------------------------------------------------
template <int BM, int BN, int MODE, bool RELU>
__global__ __launch_bounds__(256) void mm_split(
    const ushort* __restrict__ a_hi, const ushort* __restrict__ a_lo,
    const ushort* __restrict__ b_hi, const ushort* __restrict__ b_lo,
    const float* __restrict__ bias,
    float* __restrict__ Cf, ushort* __restrict__ c_hi, ushort* __restrict__ c_lo,
    int M, int N, int K) {
  constexpr int MI = BM / 32;
  constexpr int NJ = BN / 32;
  __shared__ ushort As[2][BM * 32];
  __shared__ ushort Bs[2][BN * 32];
  const int tid = threadIdx.x;
  const int w = tid >> 6, lane = tid & 63;
  const int wm = (w >> 1) * (BM / 2), wn = (w & 1) * (BN / 2);
  const int bm = blockIdx.y * BM, bn = blockIdx.x * BN;
  const int lrow = lane & 15, lquad = lane >> 4;

  floatx4 acc[MI][NJ];
  floatx4 zz = {0.f, 0.f, 0.f, 0.f};
#pragma unroll
  for (int i = 0; i < MI; ++i)
#pragma unroll
    for (int j = 0; j < NJ; ++j) acc[i][j] = zz;

  const int arow = tid >> 2, acol = (tid & 3) << 3;
  const ushort* pah = a_hi + (size_t)(bm + arow) * K + acol;
  const ushort* pal = a_lo + (size_t)(bm + arow) * K + acol;
  const ushort* pbh = b_hi + (size_t)(bn + arow) * K + acol;
  const ushort* pbl = b_lo + (size_t)(bn + arow) * K + acol;

  for (int k0 = 0; k0 < K; k0 += 32) {
    __syncthreads();
#pragma unroll
    for (int s = 0; s < BM / 64; ++s) {
      ld_lds16(pah + (size_t)s * 64 * K + k0, &As[0][s * 2048 + tid * 8]);
      ld_lds16(pal + (size_t)s * 64 * K + k0, &As[1][s * 2048 + tid * 8]);
    }
#pragma unroll
    for (int s = 0; s < BN / 64; ++s) {
      ld_lds16(pbh + (size_t)s * 64 * K + k0, &Bs[0][s * 2048 + tid * 8]);
      ld_lds16(pbl + (size_t)s * 64 * K + k0, &Bs[1][s * 2048 + tid * 8]);
    }
    __syncthreads();
    short8 ah[MI], al[MI], bh[NJ], bl[NJ];
#pragma unroll
    for (int i = 0; i < MI; ++i) {
      int r = (wm + i * 16 + lrow) * 32 + lquad * 8;
      ah[i] = *(const short8*)&As[0][r];
      al[i] = *(const short8*)&As[1][r];
    }
#pragma unroll
    for (int j = 0; j < NJ; ++j) {
      int r = (wn + j * 16 + lrow) * 32 + lquad * 8;
      bh[j] = *(const short8*)&Bs[0][r];
      bl[j] = *(const short8*)&Bs[1][r];
    }
#pragma unroll
    for (int i = 0; i < MI; ++i)
#pragma unroll
      for (int j = 0; j < NJ; ++j) {
        acc[i][j] = __builtin_amdgcn_mfma_f32_16x16x32_bf16(al[i], bh[j], acc[i][j], 0, 0, 0);
        acc[i][j] = __builtin_amdgcn_mfma_f32_16x16x32_bf16(ah[i], bl[j], acc[i][j], 0, 0, 0);
        acc[i][j] = __builtin_amdgcn_mfma_f32_16x16x32_bf16(ah[i], bh[j], acc[i][j], 0, 0, 0);
      }
  }

#pragma unroll
  for (int j = 0; j < NJ; ++j) {
    int col = bn + wn + j * 16 + lrow;
    float bj = bias[col];
#pragma unroll
    for (int i = 0; i < MI; ++i) {
      int row0 = bm + wm + i * 16 + lquad * 4;
#pragma unroll
      for (int r = 0; r < 4; ++r) {
        float v = acc[i][j][r] + bj;
        if (RELU) v = fmaxf(v, 0.0f);
        size_t off = (size_t)(row0 + r) * N + col;
        if constexpr (MODE & 1) Cf[off] = v;
        if constexpr (MODE & 2) {
          unsigned short hb = f2bf(v);
          c_hi[off] = hb;
          c_lo[off] = f2bf(v - bf2f(hb));
        }
      }
    }
  }
}

// ---------------------------------------------------------------------------
// Flash-style attention reading split qkv, writing split o.
// ---------------------------------------------------------------------------
__global__ __launch_bounds__(256) void attn_kernel(const ushort* __restrict__ qh,
                                                   const ushort* __restrict__ ql,
                                                   ushort* __restrict__ o_hi,
                                                   ushort* __restrict__ o_lo) {
  __shared__ float Ks[256][32];
  __shared__ float Vs[256][32];
  const int g = blockIdx.x >> 3, hh = blockIdx.x & 7;
  const int tid = threadIdx.x;
  const size_t gbase = (size_t)g * NNODE * 768;
  const float scale = 0.17677669529663687f;  // 1/sqrt(32)

  float q0[32], q1[32], o0[32], o1[32];
  {
    size_t q0o = gbase + (size_t)tid * 768 + hh * HD;
    size_t q1o = q0o + (size_t)256 * 768;
#pragma unroll
    for (int c = 0; c < 32; c += 4) {
      ushort4 a = *(const ushort4*)(qh + q0o + c);
      ushort4 b = *(const ushort4*)(ql + q0o + c);
      q0[c] = (bf2f(a.x) + bf2f(b.x)) * scale;
      q0[c + 1] = (bf2f(a.y) + bf2f(b.y)) * scale;
      q0[c + 2] = (bf2f(a.z) + bf2f(b.z)) * scale;
      q0[c + 3] = (bf2f(a.w) + bf2f(b.w)) * scale;
      ushort4 e = *(const ushort4*)(qh + q1o + c);
      ushort4 f = *(const ushort4*)(ql + q1o + c);
      q1[c] = (bf2f(e.x) + bf2f(f.x)) * scale;
      q1[c + 1] = (bf2f(e.y) + bf2f(f.y)) * scale;
      q1[c + 2] = (bf2f(e.z) + bf2f(f.z)) * scale;
      q1[c + 3] = (bf2f(e.w) + bf2f(f.w)) * scale;
    }
  }
#pragma unroll
  for (int c = 0; c < 32; ++c) { o0[c] = 0.f; o1[c] = 0.f; }
  float m0 = -1e30f, m1 = -1e30f, l0 = 0.f, l1 = 0.f;

  const int rst = tid >> 3, cst = (tid & 7) << 2;
  for (int tile = 0; tile < 2; ++tile) {
    __syncthreads();
#pragma unroll
    for (int jj = 0; jj < 8; ++jj) {
      int r = (jj << 5) + rst;
      size_t ro = gbase + (size_t)(tile * 256 + r) * 768 + hh * HD + cst;
      ushort4 kh = *(const ushort4*)(qh + ro + 256);
      ushort4 kl = *(const ushort4*)(ql + ro + 256);
      Ks[r][cst] = bf2f(kh.x) + bf2f(kl.x);
      Ks[r][cst + 1] = bf2f(kh.y) + bf2f(kl.y);
      Ks[r][cst + 2] = bf2f(kh.z) + bf2f(kl.z);
      Ks[r][cst + 3] = bf2f(kh.w) + bf2f(kl.w);
      ushort4 vh = *(const ushort4*)(qh + ro + 512);
      ushort4 vl = *(const ushort4*)(ql + ro + 512);
      Vs[r][cst] = bf2f(vh.x) + bf2f(vl.x);
      Vs[r][cst + 1] = bf2f(vh.y) + bf2f(vl.y);
      Vs[r][cst + 2] = bf2f(vh.z) + bf2f(vl.z);
      Vs[r][cst + 3] = bf2f(vh.w) + bf2f(vl.w);
    }
    __syncthreads();
    for (int j = 0; j < 256; ++j) {
      const float* kr = Ks[j];
      float p0a = 0.f, p0b = 0.f, p0c = 0.f, p0d = 0.f;
      float p1a = 0.f, p1b = 0.f, p1c = 0.f, p1d = 0.f;
#pragma unroll
      for (int c = 0; c < 32; c += 4) {
        float4 k4 = *(const float4*)(kr + c);
        p0a += q0[c] * k4.x; p0b += q0[c + 1] * k4.y; p0c += q0[c + 2] * k4.z; p0d += q0[c + 3] * k4.w;
        p1a += q1[c] * k4.x; p1b += q1[c + 1] * k4.y; p1c += q1[c + 2] * k4.z; p1d += q1[c + 3] * k4.w;
      }
      float d0 = (p0a + p0b) + (p0c + p0d);
      float d1 = (p1a + p1b) + (p1c + p1d);
      if (d0 > m0) {
        float corr = __expf(m0 - d0); m0 = d0; l0 *= corr;
#pragma unroll
        for (int c = 0; c < 32; ++c) o0[c] *= corr;
      }
      float e0 = __expf(d0 - m0); l0 += e0;
      if (d1 > m1) {
        float corr = __expf(m1 - d1); m1 = d1; l1 *= corr;
#pragma unroll
        for (int c = 0; c < 32; ++c) o1[c] *= corr;
      }
      float e1 = __expf(d1 - m1); l1 += e1;
      const float* vr = Vs[j];
#pragma unroll
      for (int c = 0; c < 32; c += 4) {
        float4 v4 = *(const float4*)(vr + c);
        o0[c] += e0 * v4.x; o0[c + 1] += e0 * v4.y; o0[c + 2] += e0 * v4.z; o0[c + 3] += e0 * v4.w;
        o1[c] += e1 * v4.x; o1[c + 1] += e1 * v4.y; o1[c + 2] += e1 * v4.z; o1[c + 3] += e1 * v4.w;
      }
    }
  }
  float i0 = 1.0f / l0, i1 = 1.0f / l1;
  size_t w0 = (size_t)(g * NNODE + tid) * EE + hh * HD;
  size_t w1 = (size_t)(g * NNODE + tid + 256) * EE + hh * HD;
#pragma unroll
  for (int c = 0; c < 32; c += 4) {
    ushort4 hv, lv;
    float v;
    unsigned short hb;
    v = o0[c] * i0;     hb = f2bf(v); hv.x = hb; lv.x = f2bf(v - bf2f(hb));
    v = o0[c + 1] * i0; hb = f2bf(v); hv.y = hb; lv.y = f2bf(v - bf2f(hb));
    v = o0[c + 2] * i0; hb = f2bf(v); hv.z = hb; lv.z = f2bf(v - bf2f(hb));
    v = o0[c + 3] * i0; hb = f2bf(v); hv.w = hb; lv.w = f2bf(v - bf2f(hb));
    *(ushort4*)(o_hi + w0 + c) = hv;
    *(ushort4*)(o_lo + w0 + c) = lv;
    v = o1[c] * i1;     hb = f2bf(v); hv.x = hb; lv.x = f2bf(v - bf2f(hb));
    v = o1[c + 1] * i1; hb = f2bf(v); hv.y = hb; lv.y = f2bf(v - bf2f(hb));
    v = o1[c + 2] * i1; hb = f2bf(v); hv.z = hb; lv.z = f2bf(v - bf2f(hb));
    v = o1[c + 3] * i1; hb = f2bf(v); hv.w = hb; lv.w = f2bf(v - bf2f(hb));
    *(ushort4*)(o_hi + w1 + c) = hv;
    *(ushort4*)(o_lo + w1 + c) = lv;
  }
}

// ---------------------------------------------------------------------------
// h = LN(h + t)*w + b ; also writes split(h). One wave per row.
// ---------------------------------------------------------------------------
__global__ __launch_bounds__(256) void ln_res_kernel(float* __restrict__ h,
                                                     const float* __restrict__ t,
                                                     const float* __restrict__ w,
                                                     const float* __restrict__ b,
                                                     ushort* __restrict__ h_hi,
                                                     ushort* __restrict__ h_lo) {
  int row = blockIdx.x * 4 + (threadIdx.x >> 6);
  int lane = threadIdx.x & 63;
  size_t off = (size_t)row * EE + (lane << 2);
  float4 hv = *(const float4*)&h[off];
  float4 tv = *(const float4*)&t[off];
  float v0 = hv.x + tv.x, v1 = hv.y + tv.y, v2 = hv.z + tv.z, v3 = hv.w + tv.w;
  float s = (v0 + v1) + (v2 + v3);
#pragma unroll
  for (int m = 32; m > 0; m >>= 1) s += __shfl_xor(s, m);
  float mu = s * (1.0f / 256.0f);
  float d0 = v0 - mu, d1 = v1 - mu, d2 = v2 - mu, d3 = v3 - mu;
  float s2 = (d0 * d0 + d1 * d1) + (d2 * d2 + d3 * d3);
#pragma unroll
  for (int m = 32; m > 0; m >>= 1) s2 += __shfl_xor(s2, m);
  float rs = 1.0f / sqrtf(s2 * (1.0f / 256.0f) + 1e-5f);
  float4 wv = *(const float4*)&w[lane << 2];
  float4 bv = *(const float4*)&b[lane << 2];
  float4 o;
  o.x = d0 * rs * wv.x + bv.x;
  o.y = d1 * rs * wv.y + bv.y;
  o.z = d2 * rs * wv.z + bv.z;
  o.w = d3 * rs * wv.w + bv.w;
  *(float4*)&h[off] = o;
  ushort4 hb4, lb4;
  unsigned short hb;
  hb = f2bf(o.x); hb4.x = hb; lb4.x = f2bf(o.x - bf2f(hb));
  hb = f2bf(o.y); hb4.y = hb; lb4.y = f2bf(o.y - bf2f(hb));
  hb = f2bf(o.z); hb4.z = hb; lb4.z = f2bf(o.z - bf2f(hb));
  hb = f2bf(o.w); hb4.w = hb; lb4.w = f2bf(o.w - bf2f(hb));
  *(ushort4*)&h_hi[off] = hb4;
  *(ushort4*)&h_lo[off] = lb4;
}

// ---------------------------------------------------------------------------
__global__ __launch_bounds__(256) void score_kernel(const float* __restrict__ h,
                                                    const float* __restrict__ sw,
                                                    const float* __restrict__ sb,
                                                    float* __restrict__ probs) {
  int row = blockIdx.x * 4 + (threadIdx.x >> 6);
  int lane = threadIdx.x & 63;
  float4 a = *(const float4*)&h[(size_t)row * EE + (lane << 2)];
  float4 w = *(const float4*)&sw[lane << 2];
  float s = (a.x * w.x + a.y * w.y) + (a.z * w.z + a.w * w.w);
#pragma unroll
  for (int m = 32; m > 0; m >>= 1) s += __shfl_xor(s, m);
  if (lane == 0) {
    float sc = s + sb[0];
    probs[row] = 1.0f / (1.0f + expf(-sc));
  }
}

// ---------------------------------------------------------------------------
// Per-graph exact top-k with jax.lax.top_k tie semantics (lower index wins).
// ---------------------------------------------------------------------------
__global__ __launch_bounds__(256) void topk_kernel(const float* __restrict__ probs,
                                                   float* __restrict__ out) {
  __shared__ unsigned long long keys[NNODE];
  __shared__ float pv[NNODE];
  __shared__ int flags[NNODE];
  __shared__ int sc[NNODE];
  const int g = blockIdx.x, tid = threadIdx.x;
  for (int i = tid; i < NNODE; i += 256) {
    float p = probs[g * NNODE + i];
    pv[i] = p;
    keys[i] = ((unsigned long long)__float_as_uint(p) << 32) |
              (unsigned long long)(~(unsigned)i);
    flags[i] = 0;
  }
  for (int k = 2; k <= NNODE; k <<= 1) {
    for (int j = k >> 1; j > 0; j >>= 1) {
      __syncthreads();
      for (int i = tid; i < NNODE; i += 256) {
        int ixj = i ^ j;
        if (ixj > i) {
          unsigned long long a = keys[i], bq = keys[ixj];
          bool desc = ((i & k) == 0);
          bool sw = desc ? (a < bq) : (a > bq);
          if (sw) { keys[i] = bq; keys[ixj] = a; }
        }
      }
    }
  }
  __syncthreads();
  if (tid < KSEL) {
    unsigned idx = ~(unsigned)(keys[tid] & 0xFFFFFFFFull);
    flags[idx] = 1;
  }
  __syncthreads();
  sc[tid] = flags[tid];
  sc[tid + 256] = flags[tid + 256];
  for (int off = 1; off < NNODE; off <<= 1) {
    __syncthreads();
    int x0 = (tid >= off) ? sc[tid - off] : 0;
    int x1 = sc[tid + 256 - off];
    int b0 = sc[tid], b1 = sc[tid + 256];
    __syncthreads();
    sc[tid] = b0 + x0;
    sc[tid + 256] = b1 + x1;
  }
  __syncthreads();
  for (int i = tid; i < NNODE; i += 256) {
    float p = pv[i];
    int f = flags[i];
    float ind = ((float)f - p) + p;
    float pf = p * ind;
    out[NEDGE + GG * KSEL + g * NNODE + i] = pf;
    if (f) out[NEDGE + g * KSEL + (sc[i] - 1)] = (float)(g * NNODE + i);
  }
}

// ---------------------------------------------------------------------------
__global__ __launch_bounds__(256) void edge_kernel(const int* __restrict__ ei,
                                                   const float* __restrict__ w,
                                                   float* __restrict__ out) {
  int e = blockIdx.x * 256 + threadIdx.x;
  const float* pf = out + NEDGE + GG * KSEL;
  out[e] = w[e] * pf[ei[e]] * pf[ei[NEDGE + e]];
}

// ---------------------------------------------------------------------------
extern "C" void kernel_launch(void* const* d_in, const int* in_sizes, int n_in,
                              void* d_out, int out_size, void* d_ws, size_t ws_size,
                              hipStream_t stream) {
  (void)in_sizes; (void)n_in; (void)out_size; (void)ws_size;
  const float* x     = (const float*)d_in[0];
  const int*   ei    = (const int*)d_in[1];
  const float* ewts  = (const float*)d_in[2];
  const float* emb_w = (const float*)d_in[3];
  const float* emb_b = (const float*)d_in[4];
  const float* qkv_w = (const float*)d_in[5];
  const float* qkv_b = (const float*)d_in[6];
  const float* out_w = (const float*)d_in[7];
  const float* out_b = (const float*)d_in[8];
  const float* ln1_w = (const float*)d_in[9];
  const float* ln1_b = (const float*)d_in[10];
  const float* ln2_w = (const float*)d_in[11];
  const float* ln2_b = (const float*)d_in[12];
  const float* ff1_w = (const float*)d_in[13];
  const float* ff1_b = (const float*)d_in[14];
  const float* ff2_w = (const float*)d_in[15];
  const float* ff2_b = (const float*)d_in[16];
  const float* sc_w  = (const float*)d_in[17];
  const float* sc_b  = (const float*)d_in[18];
  float* out = (float*)d_out;

  char* p = (char*)d_ws;
  size_t off = 0;
  auto alloc = [&](size_t bytes) { char* r = p + off; off += (bytes + 255) & ~(size_t)255; return r; };
  float*  h      = (float*)alloc((size_t)GN * EE * 4);           // 32 MiB
  ushort* h_hi   = (ushort*)alloc((size_t)GN * EE * 2);          // 16 MiB
  ushort* h_lo   = (ushort*)alloc((size_t)GN * EE * 2);          // 16 MiB
  ushort* qkv_hi = (ushort*)alloc((size_t)GN * 768 * 2);         // 48 MiB
  ushort* qkv_lo = (ushort*)alloc((size_t)GN * 768 * 2);         // 48 MiB
  char*   D      = alloc((size_t)64 * 1024 * 1024);              // 64 MiB
  ushort* we_hi = (ushort*)alloc(256 * 128 * 2);
  ushort* we_lo = (ushort*)alloc(256 * 128 * 2);
  ushort* wq_hi = (ushort*)alloc((size_t)LL * 768 * 256 * 2);
  ushort* wq_lo = (ushort*)alloc((size_t)LL * 768 * 256 * 2);
  ushort* wo_hi = (ushort*)alloc((size_t)LL * 256 * 256 * 2);
  ushort* wo_lo = (ushort*)alloc((size_t)LL * 256 * 256 * 2);
  ushort* w1_hi = (ushort*)alloc((size_t)LL * DFFN * 256 * 2);
  ushort* w1_lo = (ushort*)alloc((size_t)LL * DFFN * 256 * 2);
  ushort* w2_hi = (ushort*)alloc((size_t)LL * 256 * DFFN * 2);
  ushort* w2_lo = (ushort*)alloc((size_t)LL * 256 * DFFN * 2);

  // aliases (lifetimes disjoint):
  float*  tmp   = (float*)qkv_hi;                 // out-proj result (32 MiB < 48)
  float*  delta = (float*)qkv_hi;                 // ffn result
  ushort* o_hi  = (ushort*)D;                     // attn out hi [0,16 MiB)
  ushort* o_lo  = (ushort*)(D + (size_t)16 * 1024 * 1024);
  ushort* t_hi  = (ushort*)D;                     // ffn mid hi [0,32 MiB)
  ushort* t_lo  = (ushort*)(D + (size_t)32 * 1024 * 1024);
  ushort* x_hi  = (ushort*)D;                     // embed input [0,8 MiB)
  ushort* x_lo  = (ushort*)(D + (size_t)8 * 1024 * 1024);
  float*  probs = (float*)D;

  // ---- split inputs & weights ----
  auto split = [&](const float* src, ushort* hi, ushort* lo, size_t n) {
    int n4 = (int)(n / 4);
    split_kernel<<<(n4 + 255) / 256, 256, 0, stream>>>(src, hi, lo, n4);
  };
  split(x, x_hi, x_lo, (size_t)GN * DIN);
  split(emb_w, we_hi, we_lo, 256 * 128);
  split(qkv_w, wq_hi, wq_lo, (size_t)LL * 768 * 256);
  split(out_w, wo_hi, wo_lo, (size_t)LL * 256 * 256);
  split(ff1_w, w1_hi, w1_lo, (size_t)LL * DFFN * 256);
  split(ff2_w, w2_hi, w2_lo, (size_t)LL * 256 * DFFN);

  // ---- embed: h = x @ emb_w^T + emb_b (fp32 + split) ----
  mm_split<128, 128, 3, false><<<dim3(EE / 128, GN / 128), 256, 0, stream>>>(
      x_hi, x_lo, we_hi, we_lo, emb_b, h, h_hi, h_lo, GN, EE, DIN);

  for (int l = 0; l < LL; ++l) {
    // qkv (split only)
    mm_split<128, 128, 2, false><<<dim3(768 / 128, GN / 128), 256, 0, stream>>>(
        h_hi, h_lo, wq_hi + (size_t)l * 768 * 256, wq_lo + (size_t)l * 768 * 256,
        qkv_b + l * 768, nullptr, qkv_hi, qkv_lo, GN, 768, EE);
    attn_kernel<<<GG * NHH, 256, 0, stream>>>(qkv_hi, qkv_lo, o_hi, o_lo);
    // out-proj (fp32 -> tmp)
    mm_split<128, 128, 1, false><<<dim3(EE / 128, GN / 128), 256, 0, stream>>>(
        o_hi, o_lo, wo_hi + (size_t)l * 256 * 256, wo_lo + (size_t)l * 256 * 256,
        out_b + l * 256, tmp, nullptr, nullptr, GN, EE, EE);
    ln_res_kernel<<<GN / 4, 256, 0, stream>>>(h, tmp, ln1_w + l * EE, ln1_b + l * EE, h_hi, h_lo);
    // FFN in row chunks
    for (int c = 0; c < GN / CHUNK; ++c) {
      size_t r0 = (size_t)c * CHUNK;
      mm_split<128, 128, 2, true><<<dim3(DFFN / 128, CHUNK / 128), 256, 0, stream>>>(
          h_hi + r0 * EE, h_lo + r0 * EE,
          w1_hi + (size_t)l * DFFN * 256, w1_lo + (size_t)l * DFFN * 256,
          ff1_b + l * DFFN, nullptr, t_hi, t_lo, CHUNK, DFFN, EE);
      mm_split<64, 128, 1, false><<<dim3(EE / 128, CHUNK / 64), 256, 0, stream>>>(
          t_hi, t_lo,
          w2_hi + (size_t)l * 256 * DFFN, w2_lo + (size_t)l * 256 * DFFN,
          ff2_b + l * 256, delta + r0 * EE, nullptr, nullptr, CHUNK, EE, DFFN);
    }
    ln_res_kernel<<<GN / 4, 256, 0, stream>>>(h, delta, ln2_w + l * EE, ln2_b + l * EE, h_hi, h_lo);
  }

  score_kernel<<<GN / 4, 256, 0, stream>>>(h, sc_w, sc_b, probs);
  topk_kernel<<<GG, 256, 0, stream>>>(probs, out);
  edge_kernel<<<NEDGE / 256, 256, 0, stream>>>(ei, ewts, out);
}

// Round 3
// 3242.215 us; speedup vs baseline: 2.2485x; 1.2088x over previous
//
#include <hip/hip_runtime.h>
#include <cstdint>
#include <cstddef>

#define GN    32768
#define GG    64
#define NNODE 512
#define EE    256
#define LL    4
#define DFFN  2048
#define NHH   8
#define HD    32
#define NEDGE 524288
#define KSEL  128
#define DIN   128
#define CHUNK 8192

typedef __attribute__((ext_vector_type(8))) short short8;
typedef __attribute__((ext_vector_type(4))) float floatx4;

// ---- bf16 helpers (RNE) ---------------------------------------------------
__device__ __forceinline__ unsigned short f2bf(float x) {
  unsigned u = __float_as_uint(x);
  u = (u + 0x7FFFu + ((u >> 16) & 1u)) >> 16;
  return (unsigned short)u;
}
__device__ __forceinline__ float bf2f(unsigned short u) {
  return __uint_as_float((unsigned)u << 16);
}
__device__ __forceinline__ unsigned pack_split(float v) {
  unsigned short hb = f2bf(v);
  unsigned short lb = f2bf(v - bf2f(hb));
  return (unsigned)hb | ((unsigned)lb << 16);
}

// async global->LDS, 16B per lane
__device__ __forceinline__ void ld_lds16(const ushort* g, ushort* l) {
  __builtin_amdgcn_global_load_lds(
      (const __attribute__((address_space(1))) unsigned int*)g,
      (__attribute__((address_space(3))) unsigned int*)l, 16, 0, 0);
}

// ---------------------------------------------------------------------------
// split fp32 -> (hi, lo) bf16 pair, 4 elements/thread
// ---------------------------------------------------------------------------
__global__ __launch_bounds__(256) void split_kernel(const float* __restrict__ in,
                                                    ushort* __restrict__ hi,
                                                    ushort* __restrict__ lo, int n4) {
  int i = blockIdx.x * 256 + threadIdx.x;
  if (i >= n4) return;
  float4 v = ((const float4*)in)[i];
  ushort4 hv, lv;
  float t[4] = {v.x, v.y, v.z, v.w};
  unsigned short hb;
  hb = f2bf(t[0]); hv.x = hb; lv.x = f2bf(t[0] - bf2f(hb));
  hb = f2bf(t[1]); hv.y = hb; lv.y = f2bf(t[1] - bf2f(hb));
  hb = f2bf(t[2]); hv.z = hb; lv.z = f2bf(t[2] - bf2f(hb));
  hb = f2bf(t[3]); hv.w = hb; lv.w = f2bf(t[3] - bf2f(hb));
  ((ushort4*)hi)[i] = hv;
  ((ushort4*)lo)[i] = lv;
}

// ---------------------------------------------------------------------------
// Split-bf16 MFMA GEMM: C[M,N] = split(A)[M,K] @ split(B)[N,K]^T + bias[N]
// ---------------------------------------------------------------------------
template <int BM, int BN, int MODE, bool RELU>
__global__ __launch_bounds__(256) void mm_split(
    const ushort* __restrict__ a_hi, const ushort* __restrict__ a_lo,
    const ushort* __restrict__ b_hi, const ushort* __restrict__ b_lo,
    const float* __restrict__ bias,
    float* __restrict__ Cf, ushort* __restrict__ c_hi, ushort* __restrict__ c_lo,
    int M, int N, int K) {
  constexpr int MI = BM / 32;
  constexpr int NJ = BN / 32;
  __shared__ ushort As[2][BM * 32];
  __shared__ ushort Bs[2][BN * 32];
  const int tid = threadIdx.x;
  const int w = tid >> 6, lane = tid & 63;
  const int wm = (w >> 1) * (BM / 2), wn = (w & 1) * (BN / 2);
  const int bm = blockIdx.y * BM, bn = blockIdx.x * BN;
  const int lrow = lane & 15, lquad = lane >> 4;

  floatx4 acc[MI][NJ];
  floatx4 zz = {0.f, 0.f, 0.f, 0.f};
#pragma unroll
  for (int i = 0; i < MI; ++i)
#pragma unroll
    for (int j = 0; j < NJ; ++j) acc[i][j] = zz;

  const int arow = tid >> 2, acol = (tid & 3) << 3;
  const ushort* pah = a_hi + (size_t)(bm + arow) * K + acol;
  const ushort* pal = a_lo + (size_t)(bm + arow) * K + acol;
  const ushort* pbh = b_hi + (size_t)(bn + arow) * K + acol;
  const ushort* pbl = b_lo + (size_t)(bn + arow) * K + acol;

  for (int k0 = 0; k0 < K; k0 += 32) {
    __syncthreads();
#pragma unroll
    for (int s = 0; s < BM / 64; ++s) {
      ld_lds16(pah + (size_t)s * 64 * K + k0, &As[0][s * 2048 + tid * 8]);
      ld_lds16(pal + (size_t)s * 64 * K + k0, &As[1][s * 2048 + tid * 8]);
    }
#pragma unroll
    for (int s = 0; s < BN / 64; ++s) {
      ld_lds16(pbh + (size_t)s * 64 * K + k0, &Bs[0][s * 2048 + tid * 8]);
      ld_lds16(pbl + (size_t)s * 64 * K + k0, &Bs[1][s * 2048 + tid * 8]);
    }
    __syncthreads();
    short8 ah[MI], al[MI], bh[NJ], bl[NJ];
#pragma unroll
    for (int i = 0; i < MI; ++i) {
      int r = (wm + i * 16 + lrow) * 32 + lquad * 8;
      ah[i] = *(const short8*)&As[0][r];
      al[i] = *(const short8*)&As[1][r];
    }
#pragma unroll
    for (int j = 0; j < NJ; ++j) {
      int r = (wn + j * 16 + lrow) * 32 + lquad * 8;
      bh[j] = *(const short8*)&Bs[0][r];
      bl[j] = *(const short8*)&Bs[1][r];
    }
#pragma unroll
    for (int i = 0; i < MI; ++i)
#pragma unroll
      for (int j = 0; j < NJ; ++j) {
        acc[i][j] = __builtin_amdgcn_mfma_f32_16x16x32_bf16(al[i], bh[j], acc[i][j], 0, 0, 0);
        acc[i][j] = __builtin_amdgcn_mfma_f32_16x16x32_bf16(ah[i], bl[j], acc[i][j], 0, 0, 0);
        acc[i][j] = __builtin_amdgcn_mfma_f32_16x16x32_bf16(ah[i], bh[j], acc[i][j], 0, 0, 0);
      }
  }

#pragma unroll
  for (int j = 0; j < NJ; ++j) {
    int col = bn + wn + j * 16 + lrow;
    float bj = bias[col];
#pragma unroll
    for (int i = 0; i < MI; ++i) {
      int row0 = bm + wm + i * 16 + lquad * 4;
#pragma unroll
      for (int r = 0; r < 4; ++r) {
        float v = acc[i][j][r] + bj;
        if (RELU) v = fmaxf(v, 0.0f);
        size_t off = (size_t)(row0 + r) * N + col;
        if constexpr (MODE & 1) Cf[off] = v;
        if constexpr (MODE & 2) {
          unsigned short hb = f2bf(v);
          c_hi[off] = hb;
          c_lo[off] = f2bf(v - bf2f(hb));
        }
      }
    }
  }
}

// ---------------------------------------------------------------------------
// V transpose: qkv [node][768] (V = cols 512..767) -> vt [g][h][d][node_in_g]
// ---------------------------------------------------------------------------
__global__ __launch_bounds__(256) void transpose_v(const ushort* __restrict__ qh,
                                                   const ushort* __restrict__ ql,
                                                   ushort* __restrict__ vth,
                                                   ushort* __restrict__ vtl) {
  int node = blockIdx.x * 256 + threadIdx.x;
  int d = blockIdx.y * 2;
  int h = blockIdx.z;
  int g = node >> 9, n = node & 511;
  unsigned a = *(const unsigned*)(qh + (size_t)node * 768 + 512 + h * 32 + d);
  unsigned b = *(const unsigned*)(ql + (size_t)node * 768 + 512 + h * 32 + d);
  size_t base = ((size_t)(g * 8 + h) * 32 + d) * 512 + n;
  vth[base] = (ushort)a;        vth[base + 512] = (ushort)(a >> 16);
  vtl[base] = (ushort)b;        vtl[base + 512] = (ushort)(b >> 16);
}

// ---------------------------------------------------------------------------
// MFMA flash attention. Block = (64 q rows, head, graph); 4 waves, each owns
// one 16-row m-tile. K-tiles of 128 keys staged in LDS (split bf16, padded).
// S via 3-term split MFMA (K=32=head_dim); online softmax fully in-register
// (C-layout rows == per-lane quad rows); P -> LDS as (hi|lo<<16) u32, read
// back as A-frags (b128 + shift unpack); PV via 3-term split MFMA with
// pre-transposed V (vt global buffer). Output written as split bf16.
// ---------------------------------------------------------------------------
__global__ __launch_bounds__(256) void attn_mfma(const ushort* __restrict__ qh,
                                                 const ushort* __restrict__ ql,
                                                 const ushort* __restrict__ vth,
                                                 const ushort* __restrict__ vtl,
                                                 ushort* __restrict__ o_hi,
                                                 ushort* __restrict__ o_lo) {
  __shared__ ushort Ks[2][128 * 40];     // [hi/lo][key*40 + dim]
  __shared__ ushort Vt[2][32 * 136];     // [hi/lo][d*136 + key]
  __shared__ unsigned Pint[4][16 * 132]; // per-wave [m*132 + key], hi|lo<<16
  const int tid = threadIdx.x;
  const int w = tid >> 6, lane = tid & 63, c = lane & 15, quad = lane >> 4;
  const int qt = blockIdx.x, hh = blockIdx.y, g = blockIdx.z;
  const size_t g512 = (size_t)g * 512;
  const size_t vtbase = (size_t)(g * 8 + hh) * 32 * 512;
  const float scale = 0.17677669529663687f;  // 1/sqrt(32)

  // Q A-frags for this wave's 16 rows
  const size_t qnode = g512 + qt * 64 + w * 16 + c;
  short8 qfh = *(const short8*)(qh + qnode * 768 + hh * 32 + quad * 8);
  short8 qfl = *(const short8*)(ql + qnode * 768 + hh * 32 + quad * 8);

  floatx4 O0 = {0.f, 0.f, 0.f, 0.f}, O1 = {0.f, 0.f, 0.f, 0.f};
  float mrow[4] = {-3e38f, -3e38f, -3e38f, -3e38f};
  float lrow[4] = {0.f, 0.f, 0.f, 0.f};

  short8 stg[8];
  auto load_tile = [&](int kb) {
#pragma unroll
    for (int i = 0; i < 2; ++i) {
      int idx = tid * 2 + i;
      int key = idx >> 2, dc = (idx & 3) << 3;
      size_t go = (g512 + kb + key) * 768 + 256 + hh * 32 + dc;
      stg[i] = *(const short8*)(qh + go);
      stg[2 + i] = *(const short8*)(ql + go);
      int d = idx >> 4, kc = (idx & 15) << 3;
      size_t vo = vtbase + (size_t)d * 512 + kb + kc;
      stg[4 + i] = *(const short8*)(vth + vo);
      stg[6 + i] = *(const short8*)(vtl + vo);
    }
  };
  load_tile(0);

  for (int t = 0; t < 4; ++t) {
    if (t) __syncthreads();
#pragma unroll
    for (int i = 0; i < 2; ++i) {
      int idx = tid * 2 + i;
      int key = idx >> 2, dc = (idx & 3) << 3;
      *(short8*)&Ks[0][key * 40 + dc] = stg[i];
      *(short8*)&Ks[1][key * 40 + dc] = stg[2 + i];
      int d = idx >> 4, kc = (idx & 15) << 3;
      *(short8*)&Vt[0][d * 136 + kc] = stg[4 + i];
      *(short8*)&Vt[1][d * 136 + kc] = stg[6 + i];
    }
    __syncthreads();
    if (t < 3) load_tile((t + 1) * 128);

    // ---- S = (Q K^T) * scale : 8 n-tiles of 16x16 ----
    floatx4 S[8];
#pragma unroll
    for (int n = 0; n < 8; ++n) {
      int r = (n * 16 + c) * 40 + quad * 8;
      short8 kfh = *(const short8*)&Ks[0][r];
      short8 kfl = *(const short8*)&Ks[1][r];
      floatx4 s = {0.f, 0.f, 0.f, 0.f};
      s = __builtin_amdgcn_mfma_f32_16x16x32_bf16(qfh, kfl, s, 0, 0, 0);
      s = __builtin_amdgcn_mfma_f32_16x16x32_bf16(qfl, kfh, s, 0, 0, 0);
      s = __builtin_amdgcn_mfma_f32_16x16x32_bf16(qfh, kfh, s, 0, 0, 0);
#pragma unroll
      for (int r2 = 0; r2 < 4; ++r2) s[r2] *= scale;
      S[n] = s;
    }
    // ---- online softmax (rows = quad*4 + r, fully per-lane state) ----
    float corr[4];
#pragma unroll
    for (int r = 0; r < 4; ++r) {
      float mx = S[0][r];
#pragma unroll
      for (int n = 1; n < 8; ++n) mx = fmaxf(mx, S[n][r]);
#pragma unroll
      for (int msk = 1; msk < 16; msk <<= 1) mx = fmaxf(mx, __shfl_xor(mx, msk));
      float mn = fmaxf(mrow[r], mx);
      corr[r] = __expf(mrow[r] - mn);
      mrow[r] = mn;
    }
    float rs[4] = {0.f, 0.f, 0.f, 0.f};
#pragma unroll
    for (int n = 0; n < 8; ++n) {
#pragma unroll
      for (int r = 0; r < 4; ++r) {
        float pp = __expf(S[n][r] - mrow[r]);
        rs[r] += pp;
        Pint[w][(quad * 4 + r) * 132 + n * 16 + c] = pack_split(pp);
      }
    }
#pragma unroll
    for (int r = 0; r < 4; ++r) {
      float t2 = rs[r];
#pragma unroll
      for (int msk = 1; msk < 16; msk <<= 1) t2 += __shfl_xor(t2, msk);
      lrow[r] = lrow[r] * corr[r] + t2;
      O0[r] *= corr[r];
      O1[r] *= corr[r];
    }
    // ---- PV: O += P @ V  (2 d-tiles x 4 k-steps, 3-term split) ----
#pragma unroll
    for (int ks = 0; ks < 4; ++ks) {
      const unsigned* pp = &Pint[w][c * 132 + ks * 32 + quad * 8];
      uint4 a = *(const uint4*)pp;
      uint4 b = *(const uint4*)(pp + 4);
      union { short8 s; unsigned u[4]; } ph, pl;
      ph.u[0] = (a.x & 0xFFFFu) | (a.y << 16);
      ph.u[1] = (a.z & 0xFFFFu) | (a.w << 16);
      ph.u[2] = (b.x & 0xFFFFu) | (b.y << 16);
      ph.u[3] = (b.z & 0xFFFFu) | (b.w << 16);
      pl.u[0] = (a.x >> 16) | (a.y & 0xFFFF0000u);
      pl.u[1] = (a.z >> 16) | (a.w & 0xFFFF0000u);
      pl.u[2] = (b.x >> 16) | (b.y & 0xFFFF0000u);
      pl.u[3] = (b.z >> 16) | (b.w & 0xFFFF0000u);
      int r0 = (c)*136 + ks * 32 + quad * 8;
      int r1 = (16 + c) * 136 + ks * 32 + quad * 8;
      short8 v0h = *(const short8*)&Vt[0][r0];
      short8 v0l = *(const short8*)&Vt[1][r0];
      short8 v1h = *(const short8*)&Vt[0][r1];
      short8 v1l = *(const short8*)&Vt[1][r1];
      O0 = __builtin_amdgcn_mfma_f32_16x16x32_bf16(ph.s, v0l, O0, 0, 0, 0);
      O0 = __builtin_amdgcn_mfma_f32_16x16x32_bf16(pl.s, v0h, O0, 0, 0, 0);
      O0 = __builtin_amdgcn_mfma_f32_16x16x32_bf16(ph.s, v0h, O0, 0, 0, 0);
      O1 = __builtin_amdgcn_mfma_f32_16x16x32_bf16(ph.s, v1l, O1, 0, 0, 0);
      O1 = __builtin_amdgcn_mfma_f32_16x16x32_bf16(pl.s, v1h, O1, 0, 0, 0);
      O1 = __builtin_amdgcn_mfma_f32_16x16x32_bf16(ph.s, v1h, O1, 0, 0, 0);
    }
  }

  // ---- epilogue: normalize, split, store ----
#pragma unroll
  for (int r = 0; r < 4; ++r) {
    float inv = 1.0f / lrow[r];
    size_t node = g512 + qt * 64 + w * 16 + quad * 4 + r;
    size_t off0 = node * EE + hh * 32 + c;
    float v0 = O0[r] * inv;
    float v1 = O1[r] * inv;
    unsigned short hb0 = f2bf(v0), hb1 = f2bf(v1);
    o_hi[off0] = hb0;       o_lo[off0] = f2bf(v0 - bf2f(hb0));
    o_hi[off0 + 16] = hb1;  o_lo[off0 + 16] = f2bf(v1 - bf2f(hb1));
  }
}

// ---------------------------------------------------------------------------
// h = LN(h + t)*w + b ; also writes split(h). One wave per row.
// ---------------------------------------------------------------------------
__global__ __launch_bounds__(256) void ln_res_kernel(float* __restrict__ h,
                                                     const float* __restrict__ t,
                                                     const float* __restrict__ w,
                                                     const float* __restrict__ b,
                                                     ushort* __restrict__ h_hi,
                                                     ushort* __restrict__ h_lo) {
  int row = blockIdx.x * 4 + (threadIdx.x >> 6);
  int lane = threadIdx.x & 63;
  size_t off = (size_t)row * EE + (lane << 2);
  float4 hv = *(const float4*)&h[off];
  float4 tv = *(const float4*)&t[off];
  float v0 = hv.x + tv.x, v1 = hv.y + tv.y, v2 = hv.z + tv.z, v3 = hv.w + tv.w;
  float s = (v0 + v1) + (v2 + v3);
#pragma unroll
  for (int m = 32; m > 0; m >>= 1) s += __shfl_xor(s, m);
  float mu = s * (1.0f / 256.0f);
  float d0 = v0 - mu, d1 = v1 - mu, d2 = v2 - mu, d3 = v3 - mu;
  float s2 = (d0 * d0 + d1 * d1) + (d2 * d2 + d3 * d3);
#pragma unroll
  for (int m = 32; m > 0; m >>= 1) s2 += __shfl_xor(s2, m);
  float rs = 1.0f / sqrtf(s2 * (1.0f / 256.0f) + 1e-5f);
  float4 wv = *(const float4*)&w[lane << 2];
  float4 bv = *(const float4*)&b[lane << 2];
  float4 o;
  o.x = d0 * rs * wv.x + bv.x;
  o.y = d1 * rs * wv.y + bv.y;
  o.z = d2 * rs * wv.z + bv.z;
  o.w = d3 * rs * wv.w + bv.w;
  *(float4*)&h[off] = o;
  ushort4 hb4, lb4;
  unsigned short hb;
  hb = f2bf(o.x); hb4.x = hb; lb4.x = f2bf(o.x - bf2f(hb));
  hb = f2bf(o.y); hb4.y = hb; lb4.y = f2bf(o.y - bf2f(hb));
  hb = f2bf(o.z); hb4.z = hb; lb4.z = f2bf(o.z - bf2f(hb));
  hb = f2bf(o.w); hb4.w = hb; lb4.w = f2bf(o.w - bf2f(hb));
  *(ushort4*)&h_hi[off] = hb4;
  *(ushort4*)&h_lo[off] = lb4;
}

// ---------------------------------------------------------------------------
__global__ __launch_bounds__(256) void score_kernel(const float* __restrict__ h,
                                                    const float* __restrict__ sw,
                                                    const float* __restrict__ sb,
                                                    float* __restrict__ probs) {
  int row = blockIdx.x * 4 + (threadIdx.x >> 6);
  int lane = threadIdx.x & 63;
  float4 a = *(const float4*)&h[(size_t)row * EE + (lane << 2)];
  float4 w = *(const float4*)&sw[lane << 2];
  float s = (a.x * w.x + a.y * w.y) + (a.z * w.z + a.w * w.w);
#pragma unroll
  for (int m = 32; m > 0; m >>= 1) s += __shfl_xor(s, m);
  if (lane == 0) {
    float sc = s + sb[0];
    probs[row] = 1.0f / (1.0f + expf(-sc));
  }
}

// ---------------------------------------------------------------------------
// Per-graph exact top-k with jax.lax.top_k tie semantics (lower index wins).
// ---------------------------------------------------------------------------
__global__ __launch_bounds__(256) void topk_kernel(const float* __restrict__ probs,
                                                   float* __restrict__ out) {
  __shared__ unsigned long long keys[NNODE];
  __shared__ float pv[NNODE];
  __shared__ int flags[NNODE];
  __shared__ int sc[NNODE];
  const int g = blockIdx.x, tid = threadIdx.x;
  for (int i = tid; i < NNODE; i += 256) {
    float p = probs[g * NNODE + i];
    pv[i] = p;
    keys[i] = ((unsigned long long)__float_as_uint(p) << 32) |
              (unsigned long long)(~(unsigned)i);
    flags[i] = 0;
  }
  for (int k = 2; k <= NNODE; k <<= 1) {
    for (int j = k >> 1; j > 0; j >>= 1) {
      __syncthreads();
      for (int i = tid; i < NNODE; i += 256) {
        int ixj = i ^ j;
        if (ixj > i) {
          unsigned long long a = keys[i], bq = keys[ixj];
          bool desc = ((i & k) == 0);
          bool sw = desc ? (a < bq) : (a > bq);
          if (sw) { keys[i] = bq; keys[ixj] = a; }
        }
      }
    }
  }
  __syncthreads();
  if (tid < KSEL) {
    unsigned idx = ~(unsigned)(keys[tid] & 0xFFFFFFFFull);
    flags[idx] = 1;
  }
  __syncthreads();
  sc[tid] = flags[tid];
  sc[tid + 256] = flags[tid + 256];
  for (int off = 1; off < NNODE; off <<= 1) {
    __syncthreads();
    int x0 = (tid >= off) ? sc[tid - off] : 0;
    int x1 = sc[tid + 256 - off];
    int b0 = sc[tid], b1 = sc[tid + 256];
    __syncthreads();
    sc[tid] = b0 + x0;
    sc[tid + 256] = b1 + x1;
  }
  __syncthreads();
  for (int i = tid; i < NNODE; i += 256) {
    float p = pv[i];
    int f = flags[i];
    float ind = ((float)f - p) + p;
    float pf = p * ind;
    out[NEDGE + GG * KSEL + g * NNODE + i] = pf;
    if (f) out[NEDGE + g * KSEL + (sc[i] - 1)] = (float)(g * NNODE + i);
  }
}

// ---------------------------------------------------------------------------
__global__ __launch_bounds__(256) void edge_kernel(const int* __restrict__ ei,
                                                   const float* __restrict__ w,
                                                   float* __restrict__ out) {
  int e = blockIdx.x * 256 + threadIdx.x;
  const float* pf = out + NEDGE + GG * KSEL;
  out[e] = w[e] * pf[ei[e]] * pf[ei[NEDGE + e]];
}

// ---------------------------------------------------------------------------
extern "C" void kernel_launch(void* const* d_in, const int* in_sizes, int n_in,
                              void* d_out, int out_size, void* d_ws, size_t ws_size,
                              hipStream_t stream) {
  (void)in_sizes; (void)n_in; (void)out_size; (void)ws_size;
  const float* x     = (const float*)d_in[0];
  const int*   ei    = (const int*)d_in[1];
  const float* ewts  = (const float*)d_in[2];
  const float* emb_w = (const float*)d_in[3];
  const float* emb_b = (const float*)d_in[4];
  const float* qkv_w = (const float*)d_in[5];
  const float* qkv_b = (const float*)d_in[6];
  const float* out_w = (const float*)d_in[7];
  const float* out_b = (const float*)d_in[8];
  const float* ln1_w = (const float*)d_in[9];
  const float* ln1_b = (const float*)d_in[10];
  const float* ln2_w = (const float*)d_in[11];
  const float* ln2_b = (const float*)d_in[12];
  const float* ff1_w = (const float*)d_in[13];
  const float* ff1_b = (const float*)d_in[14];
  const float* ff2_w = (const float*)d_in[15];
  const float* ff2_b = (const float*)d_in[16];
  const float* sc_w  = (const float*)d_in[17];
  const float* sc_b  = (const float*)d_in[18];
  float* out = (float*)d_out;

  char* p = (char*)d_ws;
  size_t off = 0;
  auto alloc = [&](size_t bytes) { char* r = p + off; off += (bytes + 255) & ~(size_t)255; return r; };
  float*  h      = (float*)alloc((size_t)GN * EE * 4);           // 32 MiB
  ushort* h_hi   = (ushort*)alloc((size_t)GN * EE * 2);          // 16 MiB
  ushort* h_lo   = (ushort*)alloc((size_t)GN * EE * 2);          // 16 MiB
  ushort* qkv_hi = (ushort*)alloc((size_t)GN * 768 * 2);         // 48 MiB
  ushort* qkv_lo = (ushort*)alloc((size_t)GN * 768 * 2);         // 48 MiB
  char*   D      = alloc((size_t)64 * 1024 * 1024);              // 64 MiB
  ushort* we_hi = (ushort*)alloc(256 * 128 * 2);
  ushort* we_lo = (ushort*)alloc(256 * 128 * 2);
  ushort* wq_hi = (ushort*)alloc((size_t)LL * 768 * 256 * 2);
  ushort* wq_lo = (ushort*)alloc((size_t)LL * 768 * 256 * 2);
  ushort* wo_hi = (ushort*)alloc((size_t)LL * 256 * 256 * 2);
  ushort* wo_lo = (ushort*)alloc((size_t)LL * 256 * 256 * 2);
  ushort* w1_hi = (ushort*)alloc((size_t)LL * DFFN * 256 * 2);
  ushort* w1_lo = (ushort*)alloc((size_t)LL * DFFN * 256 * 2);
  ushort* w2_hi = (ushort*)alloc((size_t)LL * 256 * DFFN * 2);
  ushort* w2_lo = (ushort*)alloc((size_t)LL * 256 * DFFN * 2);

  // aliases (lifetimes disjoint):
  float*  tmp   = (float*)qkv_hi;                 // out-proj result
  float*  delta = (float*)qkv_hi;                 // ffn result
  ushort* o_hi  = (ushort*)D;                                       // [0,16 MiB)
  ushort* o_lo  = (ushort*)(D + (size_t)16 * 1024 * 1024);          // [16,32)
  ushort* vt_hi = (ushort*)(D + (size_t)32 * 1024 * 1024);          // [32,48)
  ushort* vt_lo = (ushort*)(D + (size_t)48 * 1024 * 1024);          // [48,64)
  ushort* t_hi  = (ushort*)D;                     // ffn mid hi [0,32 MiB)
  ushort* t_lo  = (ushort*)(D + (size_t)32 * 1024 * 1024);
  ushort* x_hi  = (ushort*)D;                     // embed input [0,8 MiB)
  ushort* x_lo  = (ushort*)(D + (size_t)8 * 1024 * 1024);
  float*  probs = (float*)D;

  // ---- split inputs & weights ----
  auto split = [&](const float* src, ushort* hi, ushort* lo, size_t n) {
    int n4 = (int)(n / 4);
    split_kernel<<<(n4 + 255) / 256, 256, 0, stream>>>(src, hi, lo, n4);
  };
  split(x, x_hi, x_lo, (size_t)GN * DIN);
  split(emb_w, we_hi, we_lo, 256 * 128);
  split(qkv_w, wq_hi, wq_lo, (size_t)LL * 768 * 256);
  split(out_w, wo_hi, wo_lo, (size_t)LL * 256 * 256);
  split(ff1_w, w1_hi, w1_lo, (size_t)LL * DFFN * 256);
  split(ff2_w, w2_hi, w2_lo, (size_t)LL * 256 * DFFN);

  // ---- embed: h = x @ emb_w^T + emb_b (fp32 + split) ----
  mm_split<128, 128, 3, false><<<dim3(EE / 128, GN / 128), 256, 0, stream>>>(
      x_hi, x_lo, we_hi, we_lo, emb_b, h, h_hi, h_lo, GN, EE, DIN);

  for (int l = 0; l < LL; ++l) {
    // qkv (split only)
    mm_split<128, 128, 2, false><<<dim3(768 / 128, GN / 128), 256, 0, stream>>>(
        h_hi, h_lo, wq_hi + (size_t)l * 768 * 256, wq_lo + (size_t)l * 768 * 256,
        qkv_b + l * 768, nullptr, qkv_hi, qkv_lo, GN, 768, EE);
    transpose_v<<<dim3(GN / 256, 16, 8), 256, 0, stream>>>(qkv_hi, qkv_lo, vt_hi, vt_lo);
    attn_mfma<<<dim3(8, 8, GG), 256, 0, stream>>>(qkv_hi, qkv_lo, vt_hi, vt_lo, o_hi, o_lo);
    // out-proj (fp32 -> tmp)
    mm_split<128, 128, 1, false><<<dim3(EE / 128, GN / 128), 256, 0, stream>>>(
        o_hi, o_lo, wo_hi + (size_t)l * 256 * 256, wo_lo + (size_t)l * 256 * 256,
        out_b + l * 256, tmp, nullptr, nullptr, GN, EE, EE);
    ln_res_kernel<<<GN / 4, 256, 0, stream>>>(h, tmp, ln1_w + l * EE, ln1_b + l * EE, h_hi, h_lo);
    // FFN in row chunks
    for (int c = 0; c < GN / CHUNK; ++c) {
      size_t r0 = (size_t)c * CHUNK;
      mm_split<128, 128, 2, true><<<dim3(DFFN / 128, CHUNK / 128), 256, 0, stream>>>(
          h_hi + r0 * EE, h_lo + r0 * EE,
          w1_hi + (size_t)l * DFFN * 256, w1_lo + (size_t)l * DFFN * 256,
          ff1_b + l * DFFN, nullptr, t_hi, t_lo, CHUNK, DFFN, EE);
      mm_split<64, 128, 1, false><<<dim3(EE / 128, CHUNK / 64), 256, 0, stream>>>(
          t_hi, t_lo,
          w2_hi + (size_t)l * 256 * DFFN, w2_lo + (size_t)l * 256 * DFFN,
          ff2_b + l * 256, delta + r0 * EE, nullptr, nullptr, CHUNK, EE, DFFN);
    }
    ln_res_kernel<<<GN / 4, 256, 0, stream>>>(h, delta, ln2_w + l * EE, ln2_b + l * EE, h_hi, h_lo);
  }

  score_kernel<<<GN / 4, 256, 0, stream>>>(h, sc_w, sc_b, probs);
  topk_kernel<<<GG, 256, 0, stream>>>(probs, out);
  edge_kernel<<<NEDGE / 256, 256, 0, stream>>>(ei, ewts, out);
}

// Round 4
// 2907.494 us; speedup vs baseline: 2.5073x; 1.1151x over previous
//
#include <hip/hip_runtime.h>
#include <cstdint>
#include <cstddef>

#define GN    32768
#define GG    64
#define NNODE 512
#define EE    256
#define LL    4
#define DFFN  2048
#define NHH   8
#define HD    32
#define NEDGE 524288
#define KSEL  128
#define DIN   128
#define CHUNK 16384

typedef __attribute__((ext_vector_type(8))) short short8;
typedef __attribute__((ext_vector_type(4))) float floatx4;

// ---- bf16 helpers (RNE) ---------------------------------------------------
__device__ __forceinline__ unsigned short f2bf(float x) {
  unsigned u = __float_as_uint(x);
  u = (u + 0x7FFFu + ((u >> 16) & 1u)) >> 16;
  return (unsigned short)u;
}
__device__ __forceinline__ float bf2f(unsigned short u) {
  return __uint_as_float((unsigned)u << 16);
}
__device__ __forceinline__ unsigned pack_split(float v) {
  unsigned short hb = f2bf(v);
  unsigned short lb = f2bf(v - bf2f(hb));
  return (unsigned)hb | ((unsigned)lb << 16);
}

// async global->LDS, 16B per lane (LDS dst must be wave-uniform base + lane*16)
__device__ __forceinline__ void ld_lds16(const ushort* g, ushort* l) {
  __builtin_amdgcn_global_load_lds(
      (const __attribute__((address_space(1))) unsigned int*)g,
      (__attribute__((address_space(3))) unsigned int*)l, 16, 0, 0);
}

// ---------------------------------------------------------------------------
// split fp32 -> (hi, lo) bf16 pair, 4 elements/thread
// ---------------------------------------------------------------------------
__global__ __launch_bounds__(256) void split_kernel(const float* __restrict__ in,
                                                    ushort* __restrict__ hi,
                                                    ushort* __restrict__ lo, int n4) {
  int i = blockIdx.x * 256 + threadIdx.x;
  if (i >= n4) return;
  float4 v = ((const float4*)in)[i];
  ushort4 hv, lv;
  float t[4] = {v.x, v.y, v.z, v.w};
  unsigned short hb;
  hb = f2bf(t[0]); hv.x = hb; lv.x = f2bf(t[0] - bf2f(hb));
  hb = f2bf(t[1]); hv.y = hb; lv.y = f2bf(t[1] - bf2f(hb));
  hb = f2bf(t[2]); hv.z = hb; lv.z = f2bf(t[2] - bf2f(hb));
  hb = f2bf(t[3]); hv.w = hb; lv.w = f2bf(t[3] - bf2f(hb));
  ((ushort4*)hi)[i] = hv;
  ((ushort4*)lo)[i] = lv;
}

// ---------------------------------------------------------------------------
// Split-bf16 MFMA GEMM: C[M,N] = split(A)[M,K] @ split(B)[N,K]^T + bias[N]
// XOR-swizzled LDS (kb ^= (row>>1)&3): frag b128 reads hit 8 banks (2-way,
// free) instead of 2 banks (8-way). VT: also scatter cols>=512 into vt[].
// ---------------------------------------------------------------------------
template <int BM, int BN, int MODE, bool RELU, bool VT>
__global__ __launch_bounds__(256) void mm_split(
    const ushort* __restrict__ a_hi, const ushort* __restrict__ a_lo,
    const ushort* __restrict__ b_hi, const ushort* __restrict__ b_lo,
    const float* __restrict__ bias,
    float* __restrict__ Cf, ushort* __restrict__ c_hi, ushort* __restrict__ c_lo,
    ushort* __restrict__ vth, ushort* __restrict__ vtl,
    int M, int N, int K) {
  constexpr int MI = BM / 32;
  constexpr int NJ = BN / 32;
  __shared__ ushort As[2][BM * 32];
  __shared__ ushort Bs[2][BN * 32];
  const int tid = threadIdx.x;
  const int w = tid >> 6, lane = tid & 63;
  const int wm = (w >> 1) * (BM / 2), wn = (w & 1) * (BN / 2);
  const int bm = blockIdx.y * BM, bn = blockIdx.x * BN;
  const int lrow = lane & 15, lquad = lane >> 4;

  floatx4 acc[MI][NJ];
  floatx4 zz = {0.f, 0.f, 0.f, 0.f};
#pragma unroll
  for (int i = 0; i < MI; ++i)
#pragma unroll
    for (int j = 0; j < NJ; ++j) acc[i][j] = zz;

  const int arow = tid >> 2;
  const int acol = (((tid & 3) ^ ((arow >> 1) & 3)) << 3);  // swizzled source col
  const ushort* pah = a_hi + (size_t)(bm + arow) * K + acol;
  const ushort* pal = a_lo + (size_t)(bm + arow) * K + acol;
  const ushort* pbh = b_hi + (size_t)(bn + arow) * K + acol;
  const ushort* pbl = b_lo + (size_t)(bn + arow) * K + acol;

  for (int k0 = 0; k0 < K; k0 += 32) {
    __syncthreads();
#pragma unroll
    for (int s = 0; s < BM / 64; ++s) {
      ld_lds16(pah + (size_t)s * 64 * K + k0, &As[0][s * 2048 + tid * 8]);
      ld_lds16(pal + (size_t)s * 64 * K + k0, &As[1][s * 2048 + tid * 8]);
    }
#pragma unroll
    for (int s = 0; s < BN / 64; ++s) {
      ld_lds16(pbh + (size_t)s * 64 * K + k0, &Bs[0][s * 2048 + tid * 8]);
      ld_lds16(pbl + (size_t)s * 64 * K + k0, &Bs[1][s * 2048 + tid * 8]);
    }
    __syncthreads();
    short8 ah[MI], al[MI], bh[NJ], bl[NJ];
#pragma unroll
    for (int i = 0; i < MI; ++i) {
      int rr = wm + i * 16 + lrow;
      int r = rr * 32 + ((lquad ^ ((rr >> 1) & 3)) << 3);
      ah[i] = *(const short8*)&As[0][r];
      al[i] = *(const short8*)&As[1][r];
    }
#pragma unroll
    for (int j = 0; j < NJ; ++j) {
      int rr = wn + j * 16 + lrow;
      int r = rr * 32 + ((lquad ^ ((rr >> 1) & 3)) << 3);
      bh[j] = *(const short8*)&Bs[0][r];
      bl[j] = *(const short8*)&Bs[1][r];
    }
#pragma unroll
    for (int i = 0; i < MI; ++i)
#pragma unroll
      for (int j = 0; j < NJ; ++j) {
        acc[i][j] = __builtin_amdgcn_mfma_f32_16x16x32_bf16(al[i], bh[j], acc[i][j], 0, 0, 0);
        acc[i][j] = __builtin_amdgcn_mfma_f32_16x16x32_bf16(ah[i], bl[j], acc[i][j], 0, 0, 0);
        acc[i][j] = __builtin_amdgcn_mfma_f32_16x16x32_bf16(ah[i], bh[j], acc[i][j], 0, 0, 0);
      }
  }

#pragma unroll
  for (int j = 0; j < NJ; ++j) {
    int col = bn + wn + j * 16 + lrow;
    float bj = bias[col];
#pragma unroll
    for (int i = 0; i < MI; ++i) {
      int row0 = bm + wm + i * 16 + lquad * 4;
#pragma unroll
      for (int r = 0; r < 4; ++r) {
        float v = acc[i][j][r] + bj;
        if (RELU) v = fmaxf(v, 0.0f);
        size_t off = (size_t)(row0 + r) * N + col;
        if constexpr (MODE & 1) Cf[off] = v;
        if constexpr (MODE & 2) {
          unsigned short hb = f2bf(v);
          unsigned short lb = f2bf(v - bf2f(hb));
          c_hi[off] = hb;
          c_lo[off] = lb;
          if constexpr (VT) {
            if (col >= 512) {
              int hd = col - 512;
              int row = row0 + r;
              size_t vo = ((size_t)((row >> 9) * 8 + (hd >> 5)) * 32 + (hd & 31)) * 512 + (row & 511);
              vth[vo] = hb;
              vtl[vo] = lb;
            }
          }
        }
      }
    }
  }
}

// ---------------------------------------------------------------------------
// Split GEMM + bias + residual + LayerNorm fused epilogue.
// C[M,256] = A[M,K] @ B[256,K]^T + bias; h = LN(h + C)*lnw + lnb (+ split out)
// BM=32, BN=256 (full row -> row LN in-block). Waves: 4 col-slices of 64.
// ---------------------------------------------------------------------------
__global__ __launch_bounds__(256) void mm_ln(
    const ushort* __restrict__ a_hi, const ushort* __restrict__ a_lo,
    const ushort* __restrict__ b_hi, const ushort* __restrict__ b_lo,
    const float* __restrict__ bias, const float* __restrict__ lnw,
    const float* __restrict__ lnb, float* __restrict__ hbuf,
    ushort* __restrict__ hhi, ushort* __restrict__ hlo, int K) {
  __shared__ ushort As[2][32 * 32];
  __shared__ ushort Bs[2][256 * 32];
  __shared__ float rsum[32], rsq[32], muA[32], rsA[32];
  const int tid = threadIdx.x;
  const int w = tid >> 6, lane = tid & 63;
  const int wn = w * 64;
  const int bm = blockIdx.x * 32;
  const int lr = lane & 15, quad = lane >> 4;

  floatx4 acc[2][4];
  floatx4 zz = {0.f, 0.f, 0.f, 0.f};
#pragma unroll
  for (int i = 0; i < 2; ++i)
#pragma unroll
    for (int j = 0; j < 4; ++j) acc[i][j] = zz;

  if (tid < 32) { rsum[tid] = 0.f; rsq[tid] = 0.f; }

  const int aidx = tid & 127;
  const int arow = aidx >> 2;
  const int aacol = (((aidx & 3) ^ ((arow >> 1) & 3)) << 3);
  const ushort* pa = ((tid >> 7) ? a_lo : a_hi) + (size_t)(bm + arow) * K + aacol;
  ushort* adst = &As[tid >> 7][aidx * 8];
  const int brow = tid >> 2;
  const int bcol = (((tid & 3) ^ ((brow >> 1) & 3)) << 3);

  for (int k0 = 0; k0 < K; k0 += 32) {
    __syncthreads();
    ld_lds16(pa + k0, adst);
#pragma unroll
    for (int s = 0; s < 4; ++s) {
      ld_lds16(b_hi + (size_t)(s * 64 + brow) * K + bcol + k0, &Bs[0][s * 2048 + tid * 8]);
      ld_lds16(b_lo + (size_t)(s * 64 + brow) * K + bcol + k0, &Bs[1][s * 2048 + tid * 8]);
    }
    __syncthreads();
    short8 ah[2], al[2], bh[4], bl[4];
#pragma unroll
    for (int i = 0; i < 2; ++i) {
      int rr = i * 16 + lr;
      int r = rr * 32 + ((quad ^ ((rr >> 1) & 3)) << 3);
      ah[i] = *(const short8*)&As[0][r];
      al[i] = *(const short8*)&As[1][r];
    }
#pragma unroll
    for (int j = 0; j < 4; ++j) {
      int rr = wn + j * 16 + lr;
      int r = rr * 32 + ((quad ^ ((rr >> 1) & 3)) << 3);
      bh[j] = *(const short8*)&Bs[0][r];
      bl[j] = *(const short8*)&Bs[1][r];
    }
#pragma unroll
    for (int i = 0; i < 2; ++i)
#pragma unroll
      for (int j = 0; j < 4; ++j) {
        acc[i][j] = __builtin_amdgcn_mfma_f32_16x16x32_bf16(al[i], bh[j], acc[i][j], 0, 0, 0);
        acc[i][j] = __builtin_amdgcn_mfma_f32_16x16x32_bf16(ah[i], bl[j], acc[i][j], 0, 0, 0);
        acc[i][j] = __builtin_amdgcn_mfma_f32_16x16x32_bf16(ah[i], bh[j], acc[i][j], 0, 0, 0);
      }
  }

  // ---- epilogue: v = acc + bias + residual; row LN; write h + split ----
#pragma unroll
  for (int i = 0; i < 2; ++i) {
#pragma unroll
    for (int r = 0; r < 4; ++r) {
      int ridx = i * 16 + quad * 4 + r;
      float sp = 0.f, qp = 0.f;
#pragma unroll
      for (int j = 0; j < 4; ++j) {
        int col = wn + j * 16 + lr;
        float v = acc[i][j][r] + bias[col] + hbuf[(size_t)(bm + ridx) * EE + col];
        acc[i][j][r] = v;
        sp += v;
        qp += v * v;
      }
#pragma unroll
      for (int m = 1; m < 16; m <<= 1) { sp += __shfl_xor(sp, m); qp += __shfl_xor(qp, m); }
      if (lr == 0) { atomicAdd(&rsum[ridx], sp); atomicAdd(&rsq[ridx], qp); }
    }
  }
  __syncthreads();
  if (tid < 32) {
    float mu = rsum[tid] * (1.0f / 256.0f);
    float var = rsq[tid] * (1.0f / 256.0f) - mu * mu;
    muA[tid] = mu;
    rsA[tid] = 1.0f / sqrtf(var + 1e-5f);
  }
  __syncthreads();
#pragma unroll
  for (int i = 0; i < 2; ++i) {
#pragma unroll
    for (int r = 0; r < 4; ++r) {
      int ridx = i * 16 + quad * 4 + r;
      float mu = muA[ridx], rsv = rsA[ridx];
#pragma unroll
      for (int j = 0; j < 4; ++j) {
        int col = wn + j * 16 + lr;
        float o = (acc[i][j][r] - mu) * rsv * lnw[col] + lnb[col];
        size_t off = (size_t)(bm + ridx) * EE + col;
        hbuf[off] = o;
        unsigned short hb = f2bf(o);
        hhi[off] = hb;
        hlo[off] = f2bf(o - bf2f(hb));
      }
    }
  }
}

// ---------------------------------------------------------------------------
// MFMA flash attention, q-tile=128 (halved K/V re-reads), chunked softmax/PV
// (32-key chunks; wave-local Pint, no extra barriers). LDS ~46.6KB -> 3/CU.
// ---------------------------------------------------------------------------
__global__ __launch_bounds__(256) void attn_mfma(const ushort* __restrict__ qh,
                                                 const ushort* __restrict__ ql,
                                                 const ushort* __restrict__ vth,
                                                 const ushort* __restrict__ vtl,
                                                 ushort* __restrict__ o_hi,
                                                 ushort* __restrict__ o_lo) {
  __shared__ ushort Ks[2][128 * 40];     // [hi/lo][key*40 + dim]
  __shared__ ushort Vt[2][32 * 136];     // [hi/lo][d*136 + key]
  __shared__ unsigned Pint[4][16 * 36];  // per-wave chunk [m*36 + key], hi|lo<<16
  const int tid = threadIdx.x;
  const int w = tid >> 6, lane = tid & 63, c = lane & 15, quad = lane >> 4;
  const int qt = blockIdx.x, hh = blockIdx.y, g = blockIdx.z;
  const size_t g512 = (size_t)g * 512;
  const size_t vtbase = (size_t)(g * 8 + hh) * 32 * 512;
  const int m0 = qt * 128 + w * 32;
  const float scale = 0.17677669529663687f;  // 1/sqrt(32)

  short8 qfh[2], qfl[2];
#pragma unroll
  for (int mi = 0; mi < 2; ++mi) {
    size_t node = g512 + m0 + mi * 16 + c;
    qfh[mi] = *(const short8*)(qh + node * 768 + hh * 32 + quad * 8);
    qfl[mi] = *(const short8*)(ql + node * 768 + hh * 32 + quad * 8);
  }

  floatx4 O[2][2];
  floatx4 zz = {0.f, 0.f, 0.f, 0.f};
  O[0][0] = zz; O[0][1] = zz; O[1][0] = zz; O[1][1] = zz;
  float mrow[2][4], lrow[2][4];
#pragma unroll
  for (int mi = 0; mi < 2; ++mi)
#pragma unroll
    for (int r = 0; r < 4; ++r) { mrow[mi][r] = -3e38f; lrow[mi][r] = 0.f; }

  short8 stg[8];
  auto load_tile = [&](int kb) {
#pragma unroll
    for (int i = 0; i < 2; ++i) {
      int idx = tid * 2 + i;
      int key = idx >> 2, dc = (idx & 3) << 3;
      size_t go = (g512 + kb + key) * 768 + 256 + hh * 32 + dc;
      stg[i] = *(const short8*)(qh + go);
      stg[2 + i] = *(const short8*)(ql + go);
      int d = idx >> 4, kc = (idx & 15) << 3;
      size_t vo = vtbase + (size_t)d * 512 + kb + kc;
      stg[4 + i] = *(const short8*)(vth + vo);
      stg[6 + i] = *(const short8*)(vtl + vo);
    }
  };
  load_tile(0);

  for (int t = 0; t < 4; ++t) {
    if (t) __syncthreads();
#pragma unroll
    for (int i = 0; i < 2; ++i) {
      int idx = tid * 2 + i;
      int key = idx >> 2, dc = (idx & 3) << 3;
      *(short8*)&Ks[0][key * 40 + dc] = stg[i];
      *(short8*)&Ks[1][key * 40 + dc] = stg[2 + i];
      int d = idx >> 4, kc = (idx & 15) << 3;
      *(short8*)&Vt[0][d * 136 + kc] = stg[4 + i];
      *(short8*)&Vt[1][d * 136 + kc] = stg[6 + i];
    }
    __syncthreads();
    if (t < 3) load_tile((t + 1) * 128);

#pragma unroll
    for (int mi = 0; mi < 2; ++mi) {
#pragma unroll
      for (int cc = 0; cc < 4; ++cc) {
        // S chunk: 2 n-tiles (32 keys)
        floatx4 S[2];
#pragma unroll
        for (int nn = 0; nn < 2; ++nn) {
          int n = cc * 2 + nn;
          int r = (n * 16 + c) * 40 + quad * 8;
          short8 kfh = *(const short8*)&Ks[0][r];
          short8 kfl = *(const short8*)&Ks[1][r];
          floatx4 s = zz;
          s = __builtin_amdgcn_mfma_f32_16x16x32_bf16(qfh[mi], kfl, s, 0, 0, 0);
          s = __builtin_amdgcn_mfma_f32_16x16x32_bf16(qfl[mi], kfh, s, 0, 0, 0);
          s = __builtin_amdgcn_mfma_f32_16x16x32_bf16(qfh[mi], kfh, s, 0, 0, 0);
#pragma unroll
          for (int r2 = 0; r2 < 4; ++r2) s[r2] *= scale;
          S[nn] = s;
        }
        // online softmax update over this 32-key chunk
        float corr[4];
#pragma unroll
        for (int r = 0; r < 4; ++r) {
          float mx = fmaxf(S[0][r], S[1][r]);
#pragma unroll
          for (int msk = 1; msk < 16; msk <<= 1) mx = fmaxf(mx, __shfl_xor(mx, msk));
          float mn = fmaxf(mrow[mi][r], mx);
          corr[r] = __expf(mrow[mi][r] - mn);
          mrow[mi][r] = mn;
        }
        float rs[4] = {0.f, 0.f, 0.f, 0.f};
#pragma unroll
        for (int nn = 0; nn < 2; ++nn) {
#pragma unroll
          for (int r = 0; r < 4; ++r) {
            float pp = __expf(S[nn][r] - mrow[mi][r]);
            rs[r] += pp;
            Pint[w][(quad * 4 + r) * 36 + nn * 16 + c] = pack_split(pp);
          }
        }
#pragma unroll
        for (int r = 0; r < 4; ++r) {
          float t2 = rs[r];
#pragma unroll
          for (int msk = 1; msk < 16; msk <<= 1) t2 += __shfl_xor(t2, msk);
          lrow[mi][r] = lrow[mi][r] * corr[r] + t2;
          O[mi][0][r] *= corr[r];
          O[mi][1][r] *= corr[r];
        }
        // PV for this chunk
        const unsigned* pp = &Pint[w][c * 36 + quad * 8];
        uint4 a = *(const uint4*)pp;
        uint4 b = *(const uint4*)(pp + 4);
        union { short8 s; unsigned u[4]; } ph, pl;
        ph.u[0] = (a.x & 0xFFFFu) | (a.y << 16);
        ph.u[1] = (a.z & 0xFFFFu) | (a.w << 16);
        ph.u[2] = (b.x & 0xFFFFu) | (b.y << 16);
        ph.u[3] = (b.z & 0xFFFFu) | (b.w << 16);
        pl.u[0] = (a.x >> 16) | (a.y & 0xFFFF0000u);
        pl.u[1] = (a.z >> 16) | (a.w & 0xFFFF0000u);
        pl.u[2] = (b.x >> 16) | (b.y & 0xFFFF0000u);
        pl.u[3] = (b.z >> 16) | (b.w & 0xFFFF0000u);
        int r0 = c * 136 + cc * 32 + quad * 8;
        int r1 = (16 + c) * 136 + cc * 32 + quad * 8;
        short8 v0h = *(const short8*)&Vt[0][r0];
        short8 v0l = *(const short8*)&Vt[1][r0];
        short8 v1h = *(const short8*)&Vt[0][r1];
        short8 v1l = *(const short8*)&Vt[1][r1];
        O[mi][0] = __builtin_amdgcn_mfma_f32_16x16x32_bf16(ph.s, v0l, O[mi][0], 0, 0, 0);
        O[mi][0] = __builtin_amdgcn_mfma_f32_16x16x32_bf16(pl.s, v0h, O[mi][0], 0, 0, 0);
        O[mi][0] = __builtin_amdgcn_mfma_f32_16x16x32_bf16(ph.s, v0h, O[mi][0], 0, 0, 0);
        O[mi][1] = __builtin_amdgcn_mfma_f32_16x16x32_bf16(ph.s, v1l, O[mi][1], 0, 0, 0);
        O[mi][1] = __builtin_amdgcn_mfma_f32_16x16x32_bf16(pl.s, v1h, O[mi][1], 0, 0, 0);
        O[mi][1] = __builtin_amdgcn_mfma_f32_16x16x32_bf16(ph.s, v1h, O[mi][1], 0, 0, 0);
      }
    }
  }

  // ---- epilogue: normalize, split, store ----
#pragma unroll
  for (int mi = 0; mi < 2; ++mi) {
#pragma unroll
    for (int r = 0; r < 4; ++r) {
      float inv = 1.0f / lrow[mi][r];
      size_t node = g512 + m0 + mi * 16 + quad * 4 + r;
      size_t off0 = node * EE + hh * 32 + c;
      float v0 = O[mi][0][r] * inv;
      float v1 = O[mi][1][r] * inv;
      unsigned short hb0 = f2bf(v0), hb1 = f2bf(v1);
      o_hi[off0] = hb0;       o_lo[off0] = f2bf(v0 - bf2f(hb0));
      o_hi[off0 + 16] = hb1;  o_lo[off0 + 16] = f2bf(v1 - bf2f(hb1));
    }
  }
}

// ---------------------------------------------------------------------------
__global__ __launch_bounds__(256) void score_kernel(const float* __restrict__ h,
                                                    const float* __restrict__ sw,
                                                    const float* __restrict__ sb,
                                                    float* __restrict__ probs) {
  int row = blockIdx.x * 4 + (threadIdx.x >> 6);
  int lane = threadIdx.x & 63;
  float4 a = *(const float4*)&h[(size_t)row * EE + (lane << 2)];
  float4 w = *(const float4*)&sw[lane << 2];
  float s = (a.x * w.x + a.y * w.y) + (a.z * w.z + a.w * w.w);
#pragma unroll
  for (int m = 32; m > 0; m >>= 1) s += __shfl_xor(s, m);
  if (lane == 0) {
    float sc = s + sb[0];
    probs[row] = 1.0f / (1.0f + expf(-sc));
  }
}

// ---------------------------------------------------------------------------
// Per-graph exact top-k with jax.lax.top_k tie semantics (lower index wins).
// ---------------------------------------------------------------------------
__global__ __launch_bounds__(256) void topk_kernel(const float* __restrict__ probs,
                                                   float* __restrict__ out) {
  __shared__ unsigned long long keys[NNODE];
  __shared__ float pv[NNODE];
  __shared__ int flags[NNODE];
  __shared__ int sc[NNODE];
  const int g = blockIdx.x, tid = threadIdx.x;
  for (int i = tid; i < NNODE; i += 256) {
    float p = probs[g * NNODE + i];
    pv[i] = p;
    keys[i] = ((unsigned long long)__float_as_uint(p) << 32) |
              (unsigned long long)(~(unsigned)i);
    flags[i] = 0;
  }
  for (int k = 2; k <= NNODE; k <<= 1) {
    for (int j = k >> 1; j > 0; j >>= 1) {
      __syncthreads();
      for (int i = tid; i < NNODE; i += 256) {
        int ixj = i ^ j;
        if (ixj > i) {
          unsigned long long a = keys[i], bq = keys[ixj];
          bool desc = ((i & k) == 0);
          bool sw = desc ? (a < bq) : (a > bq);
          if (sw) { keys[i] = bq; keys[ixj] = a; }
        }
      }
    }
  }
  __syncthreads();
  if (tid < KSEL) {
    unsigned idx = ~(unsigned)(keys[tid] & 0xFFFFFFFFull);
    flags[idx] = 1;
  }
  __syncthreads();
  sc[tid] = flags[tid];
  sc[tid + 256] = flags[tid + 256];
  for (int off = 1; off < NNODE; off <<= 1) {
    __syncthreads();
    int x0 = (tid >= off) ? sc[tid - off] : 0;
    int x1 = sc[tid + 256 - off];
    int b0 = sc[tid], b1 = sc[tid + 256];
    __syncthreads();
    sc[tid] = b0 + x0;
    sc[tid + 256] = b1 + x1;
  }
  __syncthreads();
  for (int i = tid; i < NNODE; i += 256) {
    float p = pv[i];
    int f = flags[i];
    float ind = ((float)f - p) + p;
    float pf = p * ind;
    out[NEDGE + GG * KSEL + g * NNODE + i] = pf;
    if (f) out[NEDGE + g * KSEL + (sc[i] - 1)] = (float)(g * NNODE + i);
  }
}

// ---------------------------------------------------------------------------
__global__ __launch_bounds__(256) void edge_kernel(const int* __restrict__ ei,
                                                   const float* __restrict__ w,
                                                   float* __restrict__ out) {
  int e = blockIdx.x * 256 + threadIdx.x;
  const float* pf = out + NEDGE + GG * KSEL;
  out[e] = w[e] * pf[ei[e]] * pf[ei[NEDGE + e]];
}

// ---------------------------------------------------------------------------
extern "C" void kernel_launch(void* const* d_in, const int* in_sizes, int n_in,
                              void* d_out, int out_size, void* d_ws, size_t ws_size,
                              hipStream_t stream) {
  (void)in_sizes; (void)n_in; (void)out_size; (void)ws_size;
  const float* x     = (const float*)d_in[0];
  const int*   ei    = (const int*)d_in[1];
  const float* ewts  = (const float*)d_in[2];
  const float* emb_w = (const float*)d_in[3];
  const float* emb_b = (const float*)d_in[4];
  const float* qkv_w = (const float*)d_in[5];
  const float* qkv_b = (const float*)d_in[6];
  const float* out_w = (const float*)d_in[7];
  const float* out_b = (const float*)d_in[8];
  const float* ln1_w = (const float*)d_in[9];
  const float* ln1_b = (const float*)d_in[10];
  const float* ln2_w = (const float*)d_in[11];
  const float* ln2_b = (const float*)d_in[12];
  const float* ff1_w = (const float*)d_in[13];
  const float* ff1_b = (const float*)d_in[14];
  const float* ff2_w = (const float*)d_in[15];
  const float* ff2_b = (const float*)d_in[16];
  const float* sc_w  = (const float*)d_in[17];
  const float* sc_b  = (const float*)d_in[18];
  float* out = (float*)d_out;

  const size_t MB = 1024 * 1024;
  char* base = (char*)d_ws;
  float*  h    = (float*)base;                       // [0,32)
  ushort* h_hi = (ushort*)(base + 32 * MB);          // [32,48)
  ushort* h_lo = (ushort*)(base + 48 * MB);          // [48,64)
  char*   R    = base + 64 * MB;                     // [64,224) multi-use
  ushort* qkv_hi = (ushort*)R;                       // [64,112)
  ushort* qkv_lo = (ushort*)(R + 48 * MB);           // [112,160)
  ushort* o_hi   = (ushort*)(R + 96 * MB);           // [160,176)
  ushort* o_lo   = (ushort*)(R + 112 * MB);          // [176,192)
  ushort* vt_hi  = (ushort*)(R + 128 * MB);          // [192,208)
  ushort* vt_lo  = (ushort*)(R + 144 * MB);          // [208,224)
  ushort* t_hi   = (ushort*)R;                       // FFN: [64,128)
  ushort* t_lo   = (ushort*)(R + 64 * MB);           // FFN: [128,192)
  ushort* x_hi   = (ushort*)R;                       // embed: [64,72)
  ushort* x_lo   = (ushort*)(R + 8 * MB);            // embed: [72,80)
  float*  probs  = (float*)R;                        // final: [64,...)
  char* W = base + 224 * MB;
  size_t woff = 0;
  auto walloc = [&](size_t bytes) { char* r = W + woff; woff += (bytes + 255) & ~(size_t)255; return (ushort*)r; };
  ushort* we_hi = walloc(256 * 128 * 2);
  ushort* we_lo = walloc(256 * 128 * 2);
  ushort* wq_hi = walloc((size_t)LL * 768 * 256 * 2);
  ushort* wq_lo = walloc((size_t)LL * 768 * 256 * 2);
  ushort* wo_hi = walloc((size_t)LL * 256 * 256 * 2);
  ushort* wo_lo = walloc((size_t)LL * 256 * 256 * 2);
  ushort* w1_hi = walloc((size_t)LL * DFFN * 256 * 2);
  ushort* w1_lo = walloc((size_t)LL * DFFN * 256 * 2);
  ushort* w2_hi = walloc((size_t)LL * 256 * DFFN * 2);
  ushort* w2_lo = walloc((size_t)LL * 256 * DFFN * 2);

  auto split = [&](const float* src, ushort* hi, ushort* lo, size_t n) {
    int n4 = (int)(n / 4);
    split_kernel<<<(n4 + 255) / 256, 256, 0, stream>>>(src, hi, lo, n4);
  };
  split(x, x_hi, x_lo, (size_t)GN * DIN);
  split(emb_w, we_hi, we_lo, 256 * 128);
  split(qkv_w, wq_hi, wq_lo, (size_t)LL * 768 * 256);
  split(out_w, wo_hi, wo_lo, (size_t)LL * 256 * 256);
  split(ff1_w, w1_hi, w1_lo, (size_t)LL * DFFN * 256);
  split(ff2_w, w2_hi, w2_lo, (size_t)LL * 256 * DFFN);

  // ---- embed: h = x @ emb_w^T + emb_b (fp32 + split) ----
  mm_split<128, 128, 3, false, false><<<dim3(EE / 128, GN / 128), 256, 0, stream>>>(
      x_hi, x_lo, we_hi, we_lo, emb_b, h, h_hi, h_lo, nullptr, nullptr, GN, EE, DIN);

  for (int l = 0; l < LL; ++l) {
    // qkv (split out + fused V transpose)
    mm_split<128, 128, 2, false, true><<<dim3(768 / 128, GN / 128), 256, 0, stream>>>(
        h_hi, h_lo, wq_hi + (size_t)l * 768 * 256, wq_lo + (size_t)l * 768 * 256,
        qkv_b + l * 768, nullptr, qkv_hi, qkv_lo, vt_hi, vt_lo, GN, 768, EE);
    attn_mfma<<<dim3(4, 8, GG), 256, 0, stream>>>(qkv_hi, qkv_lo, vt_hi, vt_lo, o_hi, o_lo);
    // out-proj + residual + LN1 fused
    mm_ln<<<GN / 32, 256, 0, stream>>>(
        o_hi, o_lo, wo_hi + (size_t)l * 256 * 256, wo_lo + (size_t)l * 256 * 256,
        out_b + l * 256, ln1_w + l * EE, ln1_b + l * EE, h, h_hi, h_lo, EE);
    // FFN in row chunks
    for (int c = 0; c < GN / CHUNK; ++c) {
      size_t r0 = (size_t)c * CHUNK;
      mm_split<128, 128, 2, true, false><<<dim3(DFFN / 128, CHUNK / 128), 256, 0, stream>>>(
          h_hi + r0 * EE, h_lo + r0 * EE,
          w1_hi + (size_t)l * DFFN * 256, w1_lo + (size_t)l * DFFN * 256,
          ff1_b + l * DFFN, nullptr, t_hi, t_lo, nullptr, nullptr, CHUNK, DFFN, EE);
      mm_ln<<<CHUNK / 32, 256, 0, stream>>>(
          t_hi, t_lo, w2_hi + (size_t)l * 256 * DFFN, w2_lo + (size_t)l * 256 * DFFN,
          ff2_b + l * 256, ln2_w + l * EE, ln2_b + l * EE,
          h + r0 * EE, h_hi + r0 * EE, h_lo + r0 * EE, DFFN);
    }
  }

  score_kernel<<<GN / 4, 256, 0, stream>>>(h, sc_w, sc_b, probs);
  topk_kernel<<<GG, 256, 0, stream>>>(probs, out);
  edge_kernel<<<NEDGE / 256, 256, 0, stream>>>(ei, ewts, out);
}